// Round 9
// baseline (474.981 us; speedup 1.0000x reference)
//
#include <hip/hip_runtime.h>
#include <hip/hip_bf16.h>
#include <cstdint>
#include <cstddef>

#define NB      128
#define RR      300
#define EMB     32

typedef __bf16 bf16x8 __attribute__((ext_vector_type(8)));
typedef float  f32x4  __attribute__((ext_vector_type(4)));
typedef unsigned short ushort8 __attribute__((ext_vector_type(8)));

__device__ __forceinline__ unsigned short f2bf(float f) {
    union { __hip_bfloat16 h; unsigned short u; } c;
    c.h = __float2bfloat16(f);
    return c.u;
}
__device__ __forceinline__ float bf2f(unsigned short u) {
    union { __hip_bfloat16 h; unsigned short u; } c;
    c.u = u;
    return __bfloat162float(c.h);
}

// ---------------------------------------------------------------------------
// helpers for the consolidated prep kernel
// ---------------------------------------------------------------------------
__device__ __forceinline__ void wpack_body(
    const float* __restrict__ w, unsigned short* __restrict__ wPT,
    int COUT, int CIN, int KK, int gpc, int idx, int total)
{
    if (idx >= total) return;
    int kk = idx & 31;
    int t  = idx >> 5;
    int oc = t % COUT;
    int kb = t / COUT;
    int g  = kb * 4 + (kk >> 3);
    int j  = kk & 7;
    int shift = g / gpc;
    int ci    = (g % gpc) * 8 + j;
    float v = (shift < KK && ci < CIN)
        ? w[(size_t)oc * CIN * KK + (size_t)ci * KK + shift] : 0.0f;
    wPT[idx] = f2bf(v);
}

__device__ __forceinline__ void fcT_body(
    const float* __restrict__ w, float* __restrict__ wT, int O, int I, int idx)
{
    if (idx >= O * I) return;
    int i = idx % I, o = idx / I;
    wT[(size_t)i * O + o] = w[idx];
}

// ---------------------------------------------------------------------------
// 1) Consolidated prep: masks + wpack x3 + ktab x3 + fcT x3 in ONE launch.
// ---------------------------------------------------------------------------
__global__ __launch_bounds__(256) void prep_k(
    const int* __restrict__ rm, unsigned long long* __restrict__ masks,
    const float* __restrict__ cw0, unsigned short* __restrict__ WP0,
    const float* __restrict__ cw1, unsigned short* __restrict__ WP1,
    const float* __restrict__ cw2, unsigned short* __restrict__ WP2,
    int* __restrict__ kt0, int* __restrict__ kt1, int* __restrict__ kt2,
    const float* __restrict__ fw0, float* __restrict__ W0T,
    const float* __restrict__ fw1, float* __restrict__ W1T,
    const float* __restrict__ fw2, float* __restrict__ W2T)
{
    const int b = blockIdx.x;
    const int t = threadIdx.x;
    if (b < 2) {
        int r = b * 256 + t;
        if (r < RR) {
            unsigned long long m = 0ull;
            #pragma unroll
            for (int k = 0; k < 64; ++k)
                if (rm[r * 64 + k]) m |= (1ull << k);
            masks[r] = m;
        }
    } else if (b < 258) {
        wpack_body(cw0, WP0, 64, 33, 25, 5, (b - 2) * 256 + t, 32 * 64 * 32);
    } else if (b < 546) {
        wpack_body(cw1, WP1, 128, 64, 9, 8, (b - 258) * 256 + t, 18 * 128 * 32);
    } else if (b < 1698) {
        wpack_body(cw2, WP2, 256, 128, 9, 16, (b - 546) * 256 + t, 36 * 256 * 32);
    } else if (b < 1699) {
        #pragma unroll
        for (int which = 0; which < 3; ++which) {
            int ngr, gpc, K, Wp, CL;
            int* dst;
            if (which == 0)      { ngr = 128; gpc = 5;  K = 5; Wp = 20; CL = 40;  dst = kt0; }
            else if (which == 1) { ngr = 72;  gpc = 8;  K = 3; Wp = 37; CL = 72;  dst = kt1; }
            else                 { ngr = 144; gpc = 16; K = 3; Wp = 19; CL = 136; dst = kt2; }
            if (t < ngr) {
                int shift = t / gpc;
                int off = 0;
                if (shift < K * K) {
                    int ky = shift / K, kx = shift % K;
                    off = (ky * Wp + kx) * CL + (t % gpc) * 8;
                }
                dst[t] = off;
            }
        }
    } else if (b < 2211) {
        fcT_body(fw0, W0T, 512, 256, (b - 1699) * 256 + t);
    } else if (b < 2723) {
        fcT_body(fw1, W1T, 256, 512, (b - 2211) * 256 + t);
    } else {
        fcT_body(fw2, W2T, 512, 256, (b - 2723) * 256 + t);
    }
}

// ---------------------------------------------------------------------------
// 2) border body (used as a tail inside pool launches)
// ---------------------------------------------------------------------------
__device__ __forceinline__ void border_body(
    unsigned short* __restrict__ base, int Hp, int Wp, int CPG, int pad,
    int sampleStride, int nborder, int idx, int total)
{
    if (idx >= total) return;
    int c8 = idx % CPG;
    int t  = idx / CPG;
    int bi = t % nborder;
    int nl = t / nborder;

    int topN = pad * Wp;
    int y, x;
    if (bi < topN) {
        y = bi / Wp; x = bi - y * Wp;
    } else if (bi < 2 * topN) {
        int b2 = bi - topN;
        y = Hp - pad + b2 / Wp; x = b2 % Wp;
    } else {
        int mid = bi - 2 * topN;
        int rowlen = 2 * pad;
        y = pad + mid / rowlen;
        int r = mid % rowlen;
        x = r < pad ? r : Wp - pad + (r - pad);
    }
    uint4 z = make_uint4(0, 0, 0, 0);
    *reinterpret_cast<uint4*>(
        &base[((size_t)nl * sampleStride) +
              ((size_t)y * Wp + x) * (CPG * 8) + c8 * 8]) = z;
}

// ---------------------------------------------------------------------------
// 3) Encode, GATHER version (proven round 5). One thread per output pixel,
//    hot-room list per band, register accumulation, no LDS atomics.
// ---------------------------------------------------------------------------
__global__ __launch_bounds__(576) void encode_k(
    const int* __restrict__ X, const unsigned long long* __restrict__ masks,
    const float* __restrict__ emb, unsigned short* __restrict__ G,
    int n0, int sampleStride)
{
    __shared__ float s_emb[RR * 36];               // 43.2 KB, 16B rows
    __shared__ unsigned s_pos[RR];
    __shared__ unsigned long long s_mask[RR];
    __shared__ unsigned short s_list[320];
    __shared__ int s_woff[9];
    __shared__ int s_cnt;

    const int nl = blockIdx.x, band = blockIdx.y;
    const int by = band * 8;
    const int n  = n0 + nl;
    const int tid = threadIdx.x;

    for (int i = tid; i < RR * 36; i += 576) {
        int r = i / 36, c = i - r * 36;
        float v = 0.0f;
        if (c == 0) v = 1.0f;
        else if (c < 33) v = emb[r * EMB + c - 1];
        s_emb[i] = v;
    }

    const int2* Xp = reinterpret_cast<const int2*>(X);
    bool hot = false;
    if (tid < RR) {
        int2 pos = Xp[n * RR + tid];
        s_pos[tid]  = (unsigned)pos.x | ((unsigned)pos.y << 16);
        s_mask[tid] = masks[tid];
        hot = (pos.y <= by + 7) && (pos.y + 7 >= by);
    }
    unsigned long long bal = __ballot(hot);
    if ((tid & 63) == 0) s_woff[tid >> 6] = (int)__popcll(bal);
    __syncthreads();
    if (tid == 0) {
        int acc = 0;
        #pragma unroll
        for (int w = 0; w < 9; ++w) { int c = s_woff[w]; s_woff[w] = acc; acc += c; }
        s_cnt = acc;
    }
    __syncthreads();
    if (hot) {
        int w = tid >> 6, b = tid & 63;
        unsigned long long before = (b == 0) ? 0ull : (bal & ((1ull << b) - 1ull));
        s_list[s_woff[w] + (int)__popcll(before)] = (unsigned short)tid;
    }
    __syncthreads();

    const int x  = tid % 72;
    const int Y  = by + tid / 72;

    f32x4 acc[9];
    #pragma unroll
    for (int k = 0; k < 9; ++k) acc[k] = (f32x4){0.f, 0.f, 0.f, 0.f};

    const int cnt = s_cnt;
    for (int idx = 0; idx < cnt; ++idx) {
        int r = s_list[idx];
        unsigned pxy = s_pos[r];
        int dxr = x - (int)(pxy & 0xffffu);
        int dyr = Y - (int)(pxy >> 16);
        if (((unsigned)dxr < 8u) && ((unsigned)dyr < 8u) &&
            ((s_mask[r] >> (dxr * 8 + dyr)) & 1ull)) {
            const f32x4* er = reinterpret_cast<const f32x4*>(&s_emb[r * 36]);
            #pragma unroll
            for (int k = 0; k < 9; ++k) acc[k] += er[k];
        }
    }

    unsigned short* Gn = G + (size_t)nl * sampleStride;
    {
        unsigned short o[40];
        #pragma unroll
        for (int k = 0; k < 9; ++k)
            #pragma unroll
            for (int j = 0; j < 4; ++j)
                o[k * 4 + j] = f2bf(acc[k][j]);
        #pragma unroll
        for (int c = 36; c < 40; ++c) o[c] = 0;
        uint4* dst = reinterpret_cast<uint4*>(
            &Gn[((size_t)(Y + 2) * 76 + (x + 2)) * 40]);
        const uint4* src = reinterpret_cast<const uint4*>(o);
        #pragma unroll
        for (int q = 0; q < 5; ++q) dst[q] = src[q];
    }

    uint4 zz4; zz4.x = zz4.y = zz4.z = zz4.w = 0;
    if (tid < 160) {
        int q = tid % 5, cell = tid / 5;
        int ci = cell & 3, rr = cell >> 2;
        int xx = ci < 2 ? ci : 72 + ci;
        uint4* dst = reinterpret_cast<uint4*>(
            &Gn[((size_t)(by + rr + 2) * 76 + xx) * 40]);
        dst[q] = zz4;
    }
    if (band == 0 || band == 8) {
        int rbase = band == 0 ? 0 : 74;
        for (int i = tid; i < 2 * 76 * 5; i += 576) {
            int q = i % 5, cell = i / 5;
            int xx = cell % 76, rr = cell / 76;
            uint4* dst = reinterpret_cast<uint4*>(
                &Gn[((size_t)(rbase + rr) * 76 + xx) * 40]);
            dst[q] = zz4;
        }
    }
}

// ---------------------------------------------------------------------------
// 4a) conv0: 24x16-spatial-tile implicit-GEMM, bf16 MFMA 16x16x32.
//     Round-6 proven body (LDS weight staging + swizzle) with weight
//     staging widened to GROUPS OF 4 ksteps (wbuf[2][4][2048], 32KB) ->
//     barrier every 4 ksteps instead of every kstep. Model: LDS-unit time
//     (~48us) and MFMA (~40us) serialize under per-kstep lockstep; 4x
//     fewer barriers lets waves drift within a group and overlap the two.
//     LDS 77.3KB -> 2 blocks/CU (reg-limited at 2 waves/SIMD anyway).
//     (Resubmission of round-8 source: container failed, no data; full
//     hazard audit found no kernel-side fault — same precedent as r3/r4.)
// ---------------------------------------------------------------------------
template<int KSTEPS>
__global__ __launch_bounds__(256, 3) void conv0_tile_k(
    const unsigned short* __restrict__ inP,
    const unsigned short* __restrict__ wPT,
    const int* __restrict__ ktab,
    const float* __restrict__ bias,
    unsigned short* __restrict__ out,
    int inSS, int outSS)
{
    constexpr int CL = 40;
    constexpr int LP = 72;
    constexpr int NGRP = KSTEPS / 4;
    __shared__ __align__(16) unsigned short slab[28 * 20 * CL];  // 44.8 KB
    __shared__ __align__(16) unsigned short wbuf[2][4][2048];    // 32 KB
    __shared__ int s_kt[KSTEPS * 4];
    unsigned short* s_c = slab;

    const int tid = threadIdx.x;
    const int tl  = blockIdx.x;
    const int nl  = blockIdx.y;
    const int tyi = tl / 5, txi = tl % 5;
    const int y0 = tyi * 24;
    const int x0 = txi < 4 ? txi * 16 : 56;

    const int lane = tid & 63, wv = tid >> 6, frow = lane & 15, fq = lane >> 4;

    if (tid < KSTEPS * 4) s_kt[tid] = ktab[tid];

    // swizzled global source offset (round-6 proven): physical LDS slot
    // P = wv*1KB + lane*16B holds logical L = P ^ (key<<4), key=(lane>>3)&7
    const int wsrc = wv * 512 + ((lane ^ ((lane >> 3) & 7)) * 8);

    // stage group 0 (ksteps 0..3) into wbuf[0]
    #pragma unroll
    for (int kk = 0; kk < 4; ++kk) {
        const unsigned short* src = wPT + (size_t)kk * 2048 + wsrc;
        __builtin_amdgcn_global_load_lds(
            (const __attribute__((address_space(1))) void*)src,
            (__attribute__((address_space(3))) void*)&wbuf[0][kk][wv * 512],
            16, 0, 0);
    }

    const unsigned short* in_n = inP + (size_t)nl * inSS;
    {
        const uint4* src = reinterpret_cast<const uint4*>(in_n);
        uint4* dst = reinterpret_cast<uint4*>(slab);
        #pragma unroll
        for (int it = 0; it < 11; ++it) {
            int q = tid + it * 256;
            if (q < 2800) {
                int r = q / 100, c = q - r * 100;
                dst[q] = src[((y0 + r) * 76 + x0) * 5 + c];
            }
        }
    }

    int ldsb[6];
    #pragma unroll
    for (int mf = 0; mf < 6; ++mf)
        ldsb[mf] = ((mf * 4 + wv) * 20 + frow) * CL;

    // swizzled read offset within a 4KB tile (ushorts), ng added as +512
    const int wrd = ((frow * 64 + fq * 16) ^ (((frow >> 1) & 7) << 4)) >> 1;

    f32x4 acc[6][4];
    #pragma unroll
    for (int a = 0; a < 6; ++a)
        #pragma unroll
        for (int b = 0; b < 4; ++b) acc[a][b] = (f32x4){0.f, 0.f, 0.f, 0.f};

    __syncthreads();   // drains vmcnt: wbuf[0] group + slab ready

    for (int g = 0; g < NGRP; ++g) {
        const int cur = g & 1;
        if (g + 1 < NGRP) {
            // prefetch the NEXT group's 4 weight tiles into the other buffer
            #pragma unroll
            for (int kk = 0; kk < 4; ++kk) {
                const unsigned short* src =
                    wPT + (size_t)((g + 1) * 4 + kk) * 2048 + wsrc;
                __builtin_amdgcn_global_load_lds(
                    (const __attribute__((address_space(1))) void*)src,
                    (__attribute__((address_space(3))) void*)
                        &wbuf[cur ^ 1][kk][wv * 512],
                    16, 0, 0);
            }
        }
        #pragma unroll
        for (int kk = 0; kk < 4; ++kk) {
            const int kb = g * 4 + kk;
            int go = s_kt[kb * 4 + fq];
            bf16x8 af[6];
            #pragma unroll
            for (int mf = 0; mf < 6; ++mf)
                af[mf] = *reinterpret_cast<const bf16x8*>(&slab[ldsb[mf] + go]);
            const unsigned short* wl = &wbuf[cur][kk][wrd];
            #pragma unroll
            for (int ng = 0; ng < 4; ++ng) {
                bf16x8 bf = *reinterpret_cast<const bf16x8*>(&wl[ng * 512]);
                #pragma unroll
                for (int mf = 0; mf < 6; ++mf)
                    acc[mf][ng] = __builtin_amdgcn_mfma_f32_16x16x32_bf16(
                        af[mf], bf, acc[mf][ng], 0, 0, 0);
            }
        }
        // one barrier per 4 ksteps: next group landed (vmcnt drained) and
        // all waves are done reading wbuf[cur] before it is re-staged.
        __syncthreads();
    }

    unsigned short* out_n = out + (size_t)nl * outSS;
    const int erow = tid >> 2, eseg = tid & 3;
    #pragma unroll
    for (int mf = 0; mf < 6; ++mf) {
        __syncthreads();
        #pragma unroll
        for (int ng = 0; ng < 4; ++ng) {
            float bv = bias[ng * 16 + frow];
            #pragma unroll
            for (int j = 0; j < 4; ++j)
                s_c[(wv * 16 + fq * 4 + j) * LP + ng * 16 + frow] =
                    f2bf(fmaxf(acc[mf][ng][j] + bv, 0.0f));
        }
        __syncthreads();
        {
            int ty = mf * 4 + (erow >> 4);
            int tx = erow & 15;
            int pos = (y0 + ty) * 72 + (x0 + tx);
            ushort8 v0 = *reinterpret_cast<const ushort8*>(
                &s_c[erow * LP + eseg * 16]);
            ushort8 v1 = *reinterpret_cast<const ushort8*>(
                &s_c[erow * LP + eseg * 16 + 8]);
            unsigned short* op = out_n + (size_t)pos * 64 + eseg * 16;
            *reinterpret_cast<ushort8*>(op) = v0;
            *reinterpret_cast<ushort8*>(op + 8) = v1;
        }
    }
}

// ---------------------------------------------------------------------------
// 4b) Generic row-slab implicit-GEMM conv (conv1/conv2), bf16 MFMA 16x16x32.
//     Single-pass epilogue (kept: it improved conv1/conv2 in round 1).
// ---------------------------------------------------------------------------
template<int MFRAG, int NG, int KH, int CPG, int CL, int SLAB, int KSTEPS>
__global__ __launch_bounds__(256, 2) void conv_mfma_k(
    const unsigned short* __restrict__ inP,
    const unsigned short* __restrict__ wPT,
    const int* __restrict__ ktab,
    const float* __restrict__ bias,
    unsigned short* __restrict__ out,
    int W, int Wp, int Mtot, int inSS, int outSS, int COUT)
{
    constexpr int Mblk = MFRAG * 64;
    constexpr int NOC  = NG * 16;
    constexpr int SEGS = NOC / 16;
    constexpr int LP   = NOC + 8;
    constexpr int CP   = CPG * 8;
    constexpr int CSZ  = Mblk * LP * 2;
    constexpr int SMEM = (SLAB * 2 > CSZ) ? SLAB * 2 : CSZ;
    __shared__ __align__(16) char smem[SMEM];
    __shared__ int s_kt[KSTEPS * 4];
    unsigned short* slab = reinterpret_cast<unsigned short*>(smem);
    unsigned short* s_c  = reinterpret_cast<unsigned short*>(smem);

    const int tid  = threadIdx.x;
    const int mb   = blockIdx.x;
    const int ocb  = blockIdx.y;
    const int nl   = blockIdx.z;
    const int lane = tid & 63;
    const int wv   = tid >> 6;
    const int frow = lane & 15;
    const int fq   = lane >> 4;

    if (tid < KSTEPS * 4) s_kt[tid] = ktab[tid];

    const int p0    = mb * Mblk;
    const int y0    = p0 / W;
    const int plast = (p0 + Mblk < Mtot ? p0 + Mblk : Mtot) - 1;
    const int rows  = plast / W - y0 + KH;

    const unsigned short* in_n =
        inP + (size_t)nl * inSS + (size_t)y0 * Wp * CP;
    const int nchunks = rows * Wp * CPG;
    for (int q = tid; q < nchunks; q += 256) {
        int pix = q / CPG, c8 = q - pix * CPG;
        uint4 v = reinterpret_cast<const uint4*>(in_n)[q];
        *reinterpret_cast<uint4*>(&slab[pix * CL + c8 * 8]) = v;
    }

    int ldsb[MFRAG];
    #pragma unroll
    for (int mf = 0; mf < MFRAG; ++mf) {
        int p  = p0 + mf * 64 + wv * 16 + frow;
        int pc = p < Mtot ? p : (Mtot - 1);
        int y  = pc / W;
        int x  = pc - y * W;
        ldsb[mf] = ((y - y0) * Wp + x) * CL;
    }
    const unsigned short* wbase =
        wPT + ((size_t)(ocb * NOC + frow)) * 32 + fq * 8;

    f32x4 acc[MFRAG][NG];
    #pragma unroll
    for (int mf = 0; mf < MFRAG; ++mf)
        #pragma unroll
        for (int ng = 0; ng < NG; ++ng)
            acc[mf][ng] = (f32x4){0.f, 0.f, 0.f, 0.f};

    __syncthreads();

    for (int kb = 0; kb < KSTEPS; ++kb) {
        int go = s_kt[kb * 4 + fq];
        bf16x8 af[MFRAG];
        #pragma unroll
        for (int mf = 0; mf < MFRAG; ++mf)
            af[mf] = *reinterpret_cast<const bf16x8*>(&slab[ldsb[mf] + go]);
        const unsigned short* wk = wbase + (size_t)kb * COUT * 32;
        #pragma unroll
        for (int ng = 0; ng < NG; ++ng) {
            bf16x8 bf = *reinterpret_cast<const bf16x8*>(wk + ng * 16 * 32);
            #pragma unroll
            for (int mf = 0; mf < MFRAG; ++mf)
                acc[mf][ng] = __builtin_amdgcn_mfma_f32_16x16x32_bf16(
                    af[mf], bf, acc[mf][ng], 0, 0, 0);
        }
    }

    // ---- single-pass epilogue ----
    __syncthreads();            // all waves done with slab
    #pragma unroll
    for (int mf = 0; mf < MFRAG; ++mf) {
        #pragma unroll
        for (int ng = 0; ng < NG; ++ng) {
            float bv = bias[ocb * NOC + ng * 16 + frow];
            #pragma unroll
            for (int j = 0; j < 4; ++j)
                s_c[(mf * 64 + wv * 16 + fq * 4 + j) * LP + ng * 16 + frow] =
                    f2bf(fmaxf(acc[mf][ng][j] + bv, 0.0f));
        }
    }
    __syncthreads();
    unsigned short* out_n = out + (size_t)nl * outSS;
    for (int t = tid; t < Mblk * SEGS; t += 256) {
        int row = t / SEGS, seg = t - row * SEGS;
        int p = p0 + row;
        if (p < Mtot) {
            ushort8 v0 = *reinterpret_cast<const ushort8*>(
                &s_c[row * LP + seg * 16]);
            ushort8 v1 = *reinterpret_cast<const ushort8*>(
                &s_c[row * LP + seg * 16 + 8]);
            unsigned short* op =
                out_n + (size_t)p * COUT + ocb * NOC + seg * 16;
            *reinterpret_cast<ushort8*>(op) = v0;
            *reinterpret_cast<ushort8*>(op + 8) = v1;
        }
    }
}

// ---------------------------------------------------------------------------
// 5) MaxPool 3x3 s2 VALID, HWC, ushort8 + fused halo-zero tail for the
//    output buffer (blocks >= npool do border zeroing; disjoint addresses).
// ---------------------------------------------------------------------------
__global__ __launch_bounds__(256) void pool_border_k(
    const unsigned short* __restrict__ in, unsigned short* __restrict__ out,
    int CG, int C, int W, int inSS,
    int HO, int WO, int Wpo, int outSS, int total,
    int npool, int bHp, int bWp, int bCPG, int bpad, int bnborder, int btotal)
{
    const int b = blockIdx.x;
    const int tidx = threadIdx.x;
    if (b >= npool) {
        border_body(out, bHp, bWp, bCPG, bpad, outSS, bnborder,
                    (b - npool) * 256 + tidx, btotal);
        return;
    }
    int idx = b * 256 + tidx;
    if (idx >= total) return;
    int cg = idx % CG;
    int t  = idx / CG;
    int x  = t % WO;
    t /= WO;
    int y  = t % HO;
    int nl = t / HO;

    const unsigned short* pin = in + (size_t)nl * inSS + cg * 8;
    ushort8 mx = {0,0,0,0,0,0,0,0};
    #pragma unroll
    for (int dy = 0; dy < 3; ++dy)
        #pragma unroll
        for (int dx = 0; dx < 3; ++dx) {
            ushort8 v = *reinterpret_cast<const ushort8*>(
                pin + ((size_t)(2 * y + dy) * W + (2 * x + dx)) * C);
            #pragma unroll
            for (int j = 0; j < 8; ++j) mx[j] = v[j] > mx[j] ? v[j] : mx[j];
        }
    *reinterpret_cast<ushort8*>(
        out + (size_t)nl * outSS +
        ((size_t)(y + 1) * Wpo + (x + 1)) * C + cg * 8) = mx;
}

// ---------------------------------------------------------------------------
// 6) Fused pool2 + GAP, v2 (grid (Bc,8), shfl reduce).
// ---------------------------------------------------------------------------
__global__ __launch_bounds__(256) void pool2gap_k(
    const unsigned short* __restrict__ in, float* __restrict__ out,
    int inSS, int n0)
{
    __shared__ float red[4][4][8];
    const int nl = blockIdx.x;
    const int cg = blockIdx.y;
    const int tid = threadIdx.x;
    const int w  = tid >> 2;
    const int cq = tid & 3;
    const int y = w >> 3, x = w & 7;

    const unsigned short* p = in + (size_t)nl * inSS + cg * 32 + cq * 8;
    ushort8 mx = {0,0,0,0,0,0,0,0};
    #pragma unroll
    for (int dy = 0; dy < 3; ++dy)
        #pragma unroll
        for (int dx = 0; dx < 3; ++dx) {
            ushort8 v = *reinterpret_cast<const ushort8*>(
                p + ((size_t)(2 * y + dy) * 17 + (2 * x + dx)) * 256);
            #pragma unroll
            for (int j = 0; j < 8; ++j) mx[j] = v[j] > mx[j] ? v[j] : mx[j];
        }
    float s[8];
    #pragma unroll
    for (int j = 0; j < 8; ++j) s[j] = bf2f(mx[j]);
    #pragma unroll
    for (int m = 4; m < 64; m <<= 1)
        #pragma unroll
        for (int j = 0; j < 8; ++j)
            s[j] += __shfl_xor(s[j], m);
    if ((tid & 63) < 4) {
        #pragma unroll
        for (int j = 0; j < 8; ++j) red[tid >> 6][tid & 3][j] = s[j];
    }
    __syncthreads();
    if (tid < 32) {
        int cq2 = tid >> 3, j = tid & 7;
        float t = red[0][cq2][j] + red[1][cq2][j] + red[2][cq2][j] + red[3][cq2][j];
        out[(size_t)(n0 + nl) * 256 + cg * 32 + cq2 * 8 + j] = t * (1.0f / 64.0f);
    }
}

// ---------------------------------------------------------------------------
// 7) Fused 3-layer FC head (256->512->256->512), one block per sample
// ---------------------------------------------------------------------------
__global__ __launch_bounds__(256) void fc_fused_k(
    const float* __restrict__ in,
    const float* __restrict__ w0T, const float* __restrict__ b0,
    const float* __restrict__ w1T, const float* __restrict__ b1,
    const float* __restrict__ w2T, const float* __restrict__ b2,
    float* __restrict__ out)
{
    __shared__ float s_in[256], s_h0[512], s_h1[256];
    const int n = blockIdx.x, t = threadIdx.x;
    s_in[t] = in[(size_t)n * 256 + t];
    __syncthreads();
    float a0 = 0.f, a1 = 0.f;
    for (int i = 0; i < 256; ++i) {
        float v = s_in[i];
        a0 += v * w0T[i * 512 + t];
        a1 += v * w0T[i * 512 + t + 256];
    }
    s_h0[t]       = fmaxf(a0 + b0[t], 0.0f);
    s_h0[t + 256] = fmaxf(a1 + b0[t + 256], 0.0f);
    __syncthreads();
    float h = 0.f;
    for (int i = 0; i < 512; ++i) h += s_h0[i] * w1T[i * 256 + t];
    s_h1[t] = fmaxf(h + b1[t], 0.0f);
    __syncthreads();
    a0 = 0.f; a1 = 0.f;
    for (int i = 0; i < 256; ++i) {
        float v = s_h1[i];
        a0 += v * w2T[i * 512 + t];
        a1 += v * w2T[i * 512 + t + 256];
    }
    out[(size_t)n * 512 + t]       = a0 + b2[t];
    out[(size_t)n * 512 + t + 256] = a1 + b2[t + 256];
}

// ---------------------------------------------------------------------------
// Launch. 9 kernels/call.
// ---------------------------------------------------------------------------
extern "C" void kernel_launch(void* const* d_in, const int* in_sizes, int n_in,
                              void* d_out, int out_size, void* d_ws, size_t ws_size,
                              hipStream_t stream)
{
    const int*   X   = (const int*)d_in[0];
    const int*   rm  = (const int*)d_in[1];
    const float* emb = (const float*)d_in[2];
    const float* cw0 = (const float*)d_in[3];
    const float* cb0 = (const float*)d_in[4];
    const float* cw1 = (const float*)d_in[5];
    const float* cb1 = (const float*)d_in[6];
    const float* cw2 = (const float*)d_in[7];
    const float* cb2 = (const float*)d_in[8];
    const float* fw0 = (const float*)d_in[9];
    const float* fb0 = (const float*)d_in[10];
    const float* fw1 = (const float*)d_in[11];
    const float* fb1 = (const float*)d_in[12];
    const float* fw2 = (const float*)d_in[13];
    const float* fb2 = (const float*)d_in[14];
    float* out = (float*)d_out;

    char* p = (char*)d_ws;
    auto alloc = [&](size_t bytes) -> char* {
        char* r = p; p += (bytes + 255) & ~(size_t)255; return r;
    };
    unsigned short* WP0 = (unsigned short*)alloc((size_t)32 * 64 * 32 * 2);
    unsigned short* WP1 = (unsigned short*)alloc((size_t)18 * 128 * 32 * 2);
    unsigned short* WP2 = (unsigned short*)alloc((size_t)36 * 256 * 32 * 2);
    int* KT0 = (int*)alloc(128 * 4);
    int* KT1 = (int*)alloc(72 * 4);
    int* KT2 = (int*)alloc(144 * 4);
    unsigned long long* MASKS = (unsigned long long*)alloc(RR * 8);
    float* W0T  = (float*)alloc((size_t)256 * 512 * 4);
    float* W1T  = (float*)alloc((size_t)512 * 256 * 4);
    float* W2T  = (float*)alloc((size_t)256 * 512 * 4);
    float* GAPB = (float*)alloc((size_t)NB * 256 * 4);
    size_t fixed_bytes = (size_t)(p - (char*)d_ws);

    const size_t A_FL = 231040, B_FL = 331776, C_FL = 133824;   // u16
    const size_t per_sample = (A_FL + B_FL + C_FL) * 2 + 768;
    int Bc = 128;
    while (Bc > 1 && fixed_bytes + (size_t)Bc * per_sample > ws_size) Bc >>= 1;

    unsigned short* bufA = (unsigned short*)alloc((size_t)Bc * A_FL * 2);
    unsigned short* bufC = (unsigned short*)alloc((size_t)Bc * C_FL * 2);
    unsigned short* bufB = (unsigned short*)alloc((size_t)Bc * B_FL * 2);

    // ---- consolidated prep (1 launch) ----
    prep_k<<<3235, 256, 0, stream>>>(
        rm, MASKS, cw0, WP0, cw1, WP1, cw2, WP2,
        KT0, KT1, KT2, fw0, W0T, fw1, W1T, fw2, W2T);

    // ---- chunked pipeline ----
    for (int n0 = 0; n0 < NB; n0 += Bc) {
        // encode (gather) -> A (HWC G [76][76][40], interior +2, halo zeroed)
        encode_k<<<dim3(Bc, 9), 576, 0, stream>>>(X, MASKS, emb, bufA, n0, (int)A_FL);

        // conv0: A -> B  (15 24x16 tiles/sample, COUT=64, 32 ksteps)
        conv0_tile_k<32><<<dim3(15, Bc), 256, 0, stream>>>(
            bufA, WP0, KT0, cb0, bufB, (int)A_FL, (int)B_FL);

        // pool0 + P0p-halo zero: B [72][72][64] -> C P0p [37][37][64]
        {
            int total = Bc * 35 * 35 * 8;
            int npool = (total + 255) / 256;
            int btotal = Bc * 144 * 8;
            int nbord = (btotal + 255) / 256;
            pool_border_k<<<npool + nbord, 256, 0, stream>>>(
                bufB, bufC, 8, 64, 72, (int)B_FL,
                35, 35, 37, (int)C_FL, total,
                npool, 37, 37, 8, 1, 144, btotal);
        }

        // conv1: C -> A  (M=1225, Mblk=256 -> 5 mblocks, COUT=128)
        conv_mfma_k<4, 8, 3, 8, 72, 29304, 18><<<dim3(5, 1, Bc), 256, 0, stream>>>(
            bufC, WP1, KT1, cb1, bufA, 35, 37,
            1225, (int)C_FL, (int)A_FL, 128);

        // pool1 + P1p-halo zero: A [35][35][128] -> C+87616 P1p [19][19][128]
        {
            int total = Bc * 17 * 17 * 16;
            int npool = (total + 255) / 256;
            int btotal = Bc * 72 * 16;
            int nbord = (btotal + 255) / 256;
            pool_border_k<<<npool + nbord, 256, 0, stream>>>(
                bufA, bufC + 87616, 16, 128, 35, (int)A_FL,
                17, 17, 19, (int)C_FL, total,
                npool, 19, 19, 16, 1, 72, btotal);
        }

        // conv2: C+87616 -> B  (M=289, single Mblk=320, 2 oc-blocks,
        //        slab = whole sample input 19x19x136 = 98KB, 256 blocks)
        conv_mfma_k<5, 8, 3, 16, 136, 49096, 36><<<dim3(1, 2, Bc), 256, 0, stream>>>(
            bufC + 87616, WP2, KT2, cb2, bufB, 17, 19,
            289, (int)C_FL, (int)B_FL, 256);

        // fused pool2 + GAP v2: (Bc, 8) blocks -> GAPB fp32
        pool2gap_k<<<dim3(Bc, 8), 256, 0, stream>>>(bufB, GAPB, (int)B_FL, n0);
    }

    // fused FC head
    fc_fused_k<<<NB, 256, 0, stream>>>(GAPB, W0T, fb0, W1T, fb1, W2T, fb2, out);
}

// Round 10
// 435.272 us; speedup vs baseline: 1.0912x; 1.0912x over previous
//
#include <hip/hip_runtime.h>
#include <hip/hip_bf16.h>
#include <cstdint>
#include <cstddef>

#define NB      128
#define RR      300
#define EMB     32

typedef __bf16 bf16x8 __attribute__((ext_vector_type(8)));
typedef float  f32x4  __attribute__((ext_vector_type(4)));
typedef unsigned short ushort8 __attribute__((ext_vector_type(8)));

__device__ __forceinline__ unsigned short f2bf(float f) {
    union { __hip_bfloat16 h; unsigned short u; } c;
    c.h = __float2bfloat16(f);
    return c.u;
}
__device__ __forceinline__ float bf2f(unsigned short u) {
    union { __hip_bfloat16 h; unsigned short u; } c;
    c.u = u;
    return __bfloat162float(c.h);
}

// ---------------------------------------------------------------------------
// helpers for the consolidated prep kernel
// ---------------------------------------------------------------------------
__device__ __forceinline__ void wpack_body(
    const float* __restrict__ w, unsigned short* __restrict__ wPT,
    int COUT, int CIN, int KK, int gpc, int idx, int total)
{
    if (idx >= total) return;
    int kk = idx & 31;
    int t  = idx >> 5;
    int oc = t % COUT;
    int kb = t / COUT;
    int g  = kb * 4 + (kk >> 3);
    int j  = kk & 7;
    int shift = g / gpc;
    int ci    = (g % gpc) * 8 + j;
    float v = (shift < KK && ci < CIN)
        ? w[(size_t)oc * CIN * KK + (size_t)ci * KK + shift] : 0.0f;
    wPT[idx] = f2bf(v);
}

__device__ __forceinline__ void fcT_body(
    const float* __restrict__ w, float* __restrict__ wT, int O, int I, int idx)
{
    if (idx >= O * I) return;
    int i = idx % I, o = idx / I;
    wT[(size_t)i * O + o] = w[idx];
}

// ---------------------------------------------------------------------------
// 1) Consolidated prep: masks + wpack x3 + ktab x3 + fcT x3 in ONE launch.
// ---------------------------------------------------------------------------
__global__ __launch_bounds__(256) void prep_k(
    const int* __restrict__ rm, unsigned long long* __restrict__ masks,
    const float* __restrict__ cw0, unsigned short* __restrict__ WP0,
    const float* __restrict__ cw1, unsigned short* __restrict__ WP1,
    const float* __restrict__ cw2, unsigned short* __restrict__ WP2,
    int* __restrict__ kt0, int* __restrict__ kt1, int* __restrict__ kt2,
    const float* __restrict__ fw0, float* __restrict__ W0T,
    const float* __restrict__ fw1, float* __restrict__ W1T,
    const float* __restrict__ fw2, float* __restrict__ W2T)
{
    const int b = blockIdx.x;
    const int t = threadIdx.x;
    if (b < 2) {
        int r = b * 256 + t;
        if (r < RR) {
            unsigned long long m = 0ull;
            #pragma unroll
            for (int k = 0; k < 64; ++k)
                if (rm[r * 64 + k]) m |= (1ull << k);
            masks[r] = m;
        }
    } else if (b < 258) {
        wpack_body(cw0, WP0, 64, 33, 25, 5, (b - 2) * 256 + t, 32 * 64 * 32);
    } else if (b < 546) {
        wpack_body(cw1, WP1, 128, 64, 9, 8, (b - 258) * 256 + t, 18 * 128 * 32);
    } else if (b < 1698) {
        wpack_body(cw2, WP2, 256, 128, 9, 16, (b - 546) * 256 + t, 36 * 256 * 32);
    } else if (b < 1699) {
        #pragma unroll
        for (int which = 0; which < 3; ++which) {
            int ngr, gpc, K, Wp, CL;
            int* dst;
            if (which == 0)      { ngr = 128; gpc = 5;  K = 5; Wp = 20; CL = 40;  dst = kt0; }
            else if (which == 1) { ngr = 72;  gpc = 8;  K = 3; Wp = 37; CL = 72;  dst = kt1; }
            else                 { ngr = 144; gpc = 16; K = 3; Wp = 19; CL = 136; dst = kt2; }
            if (t < ngr) {
                int shift = t / gpc;
                int off = 0;
                if (shift < K * K) {
                    int ky = shift / K, kx = shift % K;
                    off = (ky * Wp + kx) * CL + (t % gpc) * 8;
                }
                dst[t] = off;
            }
        }
    } else if (b < 2211) {
        fcT_body(fw0, W0T, 512, 256, (b - 1699) * 256 + t);
    } else if (b < 2723) {
        fcT_body(fw1, W1T, 256, 512, (b - 2211) * 256 + t);
    } else {
        fcT_body(fw2, W2T, 512, 256, (b - 2723) * 256 + t);
    }
}

// ---------------------------------------------------------------------------
// 2) border body (used as a tail inside pool launches)
// ---------------------------------------------------------------------------
__device__ __forceinline__ void border_body(
    unsigned short* __restrict__ base, int Hp, int Wp, int CPG, int pad,
    int sampleStride, int nborder, int idx, int total)
{
    if (idx >= total) return;
    int c8 = idx % CPG;
    int t  = idx / CPG;
    int bi = t % nborder;
    int nl = t / nborder;

    int topN = pad * Wp;
    int y, x;
    if (bi < topN) {
        y = bi / Wp; x = bi - y * Wp;
    } else if (bi < 2 * topN) {
        int b2 = bi - topN;
        y = Hp - pad + b2 / Wp; x = b2 % Wp;
    } else {
        int mid = bi - 2 * topN;
        int rowlen = 2 * pad;
        y = pad + mid / rowlen;
        int r = mid % rowlen;
        x = r < pad ? r : Wp - pad + (r - pad);
    }
    uint4 z = make_uint4(0, 0, 0, 0);
    *reinterpret_cast<uint4*>(
        &base[((size_t)nl * sampleStride) +
              ((size_t)y * Wp + x) * (CPG * 8) + c8 * 8]) = z;
}

// ---------------------------------------------------------------------------
// 3) Encode, GATHER version (proven round 5). One thread per output pixel,
//    hot-room list per band, register accumulation, no LDS atomics.
// ---------------------------------------------------------------------------
__global__ __launch_bounds__(576) void encode_k(
    const int* __restrict__ X, const unsigned long long* __restrict__ masks,
    const float* __restrict__ emb, unsigned short* __restrict__ G,
    int n0, int sampleStride)
{
    __shared__ float s_emb[RR * 36];               // 43.2 KB, 16B rows
    __shared__ unsigned s_pos[RR];
    __shared__ unsigned long long s_mask[RR];
    __shared__ unsigned short s_list[320];
    __shared__ int s_woff[9];
    __shared__ int s_cnt;

    const int nl = blockIdx.x, band = blockIdx.y;
    const int by = band * 8;
    const int n  = n0 + nl;
    const int tid = threadIdx.x;

    for (int i = tid; i < RR * 36; i += 576) {
        int r = i / 36, c = i - r * 36;
        float v = 0.0f;
        if (c == 0) v = 1.0f;
        else if (c < 33) v = emb[r * EMB + c - 1];
        s_emb[i] = v;
    }

    const int2* Xp = reinterpret_cast<const int2*>(X);
    bool hot = false;
    if (tid < RR) {
        int2 pos = Xp[n * RR + tid];
        s_pos[tid]  = (unsigned)pos.x | ((unsigned)pos.y << 16);
        s_mask[tid] = masks[tid];
        hot = (pos.y <= by + 7) && (pos.y + 7 >= by);
    }
    unsigned long long bal = __ballot(hot);
    if ((tid & 63) == 0) s_woff[tid >> 6] = (int)__popcll(bal);
    __syncthreads();
    if (tid == 0) {
        int acc = 0;
        #pragma unroll
        for (int w = 0; w < 9; ++w) { int c = s_woff[w]; s_woff[w] = acc; acc += c; }
        s_cnt = acc;
    }
    __syncthreads();
    if (hot) {
        int w = tid >> 6, b = tid & 63;
        unsigned long long before = (b == 0) ? 0ull : (bal & ((1ull << b) - 1ull));
        s_list[s_woff[w] + (int)__popcll(before)] = (unsigned short)tid;
    }
    __syncthreads();

    const int x  = tid % 72;
    const int Y  = by + tid / 72;

    f32x4 acc[9];
    #pragma unroll
    for (int k = 0; k < 9; ++k) acc[k] = (f32x4){0.f, 0.f, 0.f, 0.f};

    const int cnt = s_cnt;
    for (int idx = 0; idx < cnt; ++idx) {
        int r = s_list[idx];
        unsigned pxy = s_pos[r];
        int dxr = x - (int)(pxy & 0xffffu);
        int dyr = Y - (int)(pxy >> 16);
        if (((unsigned)dxr < 8u) && ((unsigned)dyr < 8u) &&
            ((s_mask[r] >> (dxr * 8 + dyr)) & 1ull)) {
            const f32x4* er = reinterpret_cast<const f32x4*>(&s_emb[r * 36]);
            #pragma unroll
            for (int k = 0; k < 9; ++k) acc[k] += er[k];
        }
    }

    unsigned short* Gn = G + (size_t)nl * sampleStride;
    {
        unsigned short o[40];
        #pragma unroll
        for (int k = 0; k < 9; ++k)
            #pragma unroll
            for (int j = 0; j < 4; ++j)
                o[k * 4 + j] = f2bf(acc[k][j]);
        #pragma unroll
        for (int c = 36; c < 40; ++c) o[c] = 0;
        uint4* dst = reinterpret_cast<uint4*>(
            &Gn[((size_t)(Y + 2) * 76 + (x + 2)) * 40]);
        const uint4* src = reinterpret_cast<const uint4*>(o);
        #pragma unroll
        for (int q = 0; q < 5; ++q) dst[q] = src[q];
    }

    uint4 zz4; zz4.x = zz4.y = zz4.z = zz4.w = 0;
    if (tid < 160) {
        int q = tid % 5, cell = tid / 5;
        int ci = cell & 3, rr = cell >> 2;
        int xx = ci < 2 ? ci : 72 + ci;
        uint4* dst = reinterpret_cast<uint4*>(
            &Gn[((size_t)(by + rr + 2) * 76 + xx) * 40]);
        dst[q] = zz4;
    }
    if (band == 0 || band == 8) {
        int rbase = band == 0 ? 0 : 74;
        for (int i = tid; i < 2 * 76 * 5; i += 576) {
            int q = i % 5, cell = i / 5;
            int xx = cell % 76, rr = cell / 76;
            uint4* dst = reinterpret_cast<uint4*>(
                &Gn[((size_t)(rbase + rr) * 76 + xx) * 40]);
            dst[q] = zz4;
        }
    }
}

// ---------------------------------------------------------------------------
// 4a) conv0: 24x16-spatial-tile implicit-GEMM, bf16 MFMA 16x16x32.
//     Round-6 proven body (LDS weight staging + swizzle, 94.5us) with
//     weight staging widened to GROUPS OF 2 ksteps (wbuf[2][2][2048],
//     16KB) -> barrier every 2 ksteps. Round-9 lesson: group-4's 76.5KB
//     LDS dropped residency to 1 block/CU (Occ 10.8%, 163us) — occupancy
//     change confounded the lockstep A/B. Group-2 keeps LDS at 61.4KB
//     (2 blocks/CU, same as reg limit) so barrier frequency is the ONLY
//     variable: clean test of the lockstep-amortization theory.
// ---------------------------------------------------------------------------
template<int KSTEPS>
__global__ __launch_bounds__(256, 3) void conv0_tile_k(
    const unsigned short* __restrict__ inP,
    const unsigned short* __restrict__ wPT,
    const int* __restrict__ ktab,
    const float* __restrict__ bias,
    unsigned short* __restrict__ out,
    int inSS, int outSS)
{
    constexpr int CL = 40;
    constexpr int LP = 72;
    constexpr int NGRP = KSTEPS / 2;
    __shared__ __align__(16) unsigned short slab[28 * 20 * CL];  // 44.8 KB
    __shared__ __align__(16) unsigned short wbuf[2][2][2048];    // 16 KB
    __shared__ int s_kt[KSTEPS * 4];
    unsigned short* s_c = slab;

    const int tid = threadIdx.x;
    const int tl  = blockIdx.x;
    const int nl  = blockIdx.y;
    const int tyi = tl / 5, txi = tl % 5;
    const int y0 = tyi * 24;
    const int x0 = txi < 4 ? txi * 16 : 56;

    const int lane = tid & 63, wv = tid >> 6, frow = lane & 15, fq = lane >> 4;

    if (tid < KSTEPS * 4) s_kt[tid] = ktab[tid];

    // swizzled global source offset (round-6 proven): physical LDS slot
    // P = wv*1KB + lane*16B holds logical L = P ^ (key<<4), key=(lane>>3)&7
    const int wsrc = wv * 512 + ((lane ^ ((lane >> 3) & 7)) * 8);

    // stage group 0 (ksteps 0..1) into wbuf[0]
    #pragma unroll
    for (int kk = 0; kk < 2; ++kk) {
        const unsigned short* src = wPT + (size_t)kk * 2048 + wsrc;
        __builtin_amdgcn_global_load_lds(
            (const __attribute__((address_space(1))) void*)src,
            (__attribute__((address_space(3))) void*)&wbuf[0][kk][wv * 512],
            16, 0, 0);
    }

    const unsigned short* in_n = inP + (size_t)nl * inSS;
    {
        const uint4* src = reinterpret_cast<const uint4*>(in_n);
        uint4* dst = reinterpret_cast<uint4*>(slab);
        #pragma unroll
        for (int it = 0; it < 11; ++it) {
            int q = tid + it * 256;
            if (q < 2800) {
                int r = q / 100, c = q - r * 100;
                dst[q] = src[((y0 + r) * 76 + x0) * 5 + c];
            }
        }
    }

    int ldsb[6];
    #pragma unroll
    for (int mf = 0; mf < 6; ++mf)
        ldsb[mf] = ((mf * 4 + wv) * 20 + frow) * CL;

    // swizzled read offset within a 4KB tile (ushorts), ng added as +512
    const int wrd = ((frow * 64 + fq * 16) ^ (((frow >> 1) & 7) << 4)) >> 1;

    f32x4 acc[6][4];
    #pragma unroll
    for (int a = 0; a < 6; ++a)
        #pragma unroll
        for (int b = 0; b < 4; ++b) acc[a][b] = (f32x4){0.f, 0.f, 0.f, 0.f};

    __syncthreads();   // drains vmcnt: wbuf[0] group + slab ready

    for (int g = 0; g < NGRP; ++g) {
        const int cur = g & 1;
        if (g + 1 < NGRP) {
            // prefetch the NEXT group's 2 weight tiles into the other buffer
            #pragma unroll
            for (int kk = 0; kk < 2; ++kk) {
                const unsigned short* src =
                    wPT + (size_t)((g + 1) * 2 + kk) * 2048 + wsrc;
                __builtin_amdgcn_global_load_lds(
                    (const __attribute__((address_space(1))) void*)src,
                    (__attribute__((address_space(3))) void*)
                        &wbuf[cur ^ 1][kk][wv * 512],
                    16, 0, 0);
            }
        }
        #pragma unroll
        for (int kk = 0; kk < 2; ++kk) {
            const int kb = g * 2 + kk;
            int go = s_kt[kb * 4 + fq];
            bf16x8 af[6];
            #pragma unroll
            for (int mf = 0; mf < 6; ++mf)
                af[mf] = *reinterpret_cast<const bf16x8*>(&slab[ldsb[mf] + go]);
            const unsigned short* wl = &wbuf[cur][kk][wrd];
            #pragma unroll
            for (int ng = 0; ng < 4; ++ng) {
                bf16x8 bf = *reinterpret_cast<const bf16x8*>(&wl[ng * 512]);
                #pragma unroll
                for (int mf = 0; mf < 6; ++mf)
                    acc[mf][ng] = __builtin_amdgcn_mfma_f32_16x16x32_bf16(
                        af[mf], bf, acc[mf][ng], 0, 0, 0);
            }
        }
        // one barrier per 2 ksteps: next group landed (vmcnt drained) and
        // all waves are done reading wbuf[cur] before it is re-staged.
        __syncthreads();
    }

    unsigned short* out_n = out + (size_t)nl * outSS;
    const int erow = tid >> 2, eseg = tid & 3;
    #pragma unroll
    for (int mf = 0; mf < 6; ++mf) {
        __syncthreads();
        #pragma unroll
        for (int ng = 0; ng < 4; ++ng) {
            float bv = bias[ng * 16 + frow];
            #pragma unroll
            for (int j = 0; j < 4; ++j)
                s_c[(wv * 16 + fq * 4 + j) * LP + ng * 16 + frow] =
                    f2bf(fmaxf(acc[mf][ng][j] + bv, 0.0f));
        }
        __syncthreads();
        {
            int ty = mf * 4 + (erow >> 4);
            int tx = erow & 15;
            int pos = (y0 + ty) * 72 + (x0 + tx);
            ushort8 v0 = *reinterpret_cast<const ushort8*>(
                &s_c[erow * LP + eseg * 16]);
            ushort8 v1 = *reinterpret_cast<const ushort8*>(
                &s_c[erow * LP + eseg * 16 + 8]);
            unsigned short* op = out_n + (size_t)pos * 64 + eseg * 16;
            *reinterpret_cast<ushort8*>(op) = v0;
            *reinterpret_cast<ushort8*>(op + 8) = v1;
        }
    }
}

// ---------------------------------------------------------------------------
// 4b) Generic row-slab implicit-GEMM conv (conv1/conv2), bf16 MFMA 16x16x32.
//     Single-pass epilogue (kept: it improved conv1/conv2 in round 1).
// ---------------------------------------------------------------------------
template<int MFRAG, int NG, int KH, int CPG, int CL, int SLAB, int KSTEPS>
__global__ __launch_bounds__(256, 2) void conv_mfma_k(
    const unsigned short* __restrict__ inP,
    const unsigned short* __restrict__ wPT,
    const int* __restrict__ ktab,
    const float* __restrict__ bias,
    unsigned short* __restrict__ out,
    int W, int Wp, int Mtot, int inSS, int outSS, int COUT)
{
    constexpr int Mblk = MFRAG * 64;
    constexpr int NOC  = NG * 16;
    constexpr int SEGS = NOC / 16;
    constexpr int LP   = NOC + 8;
    constexpr int CP   = CPG * 8;
    constexpr int CSZ  = Mblk * LP * 2;
    constexpr int SMEM = (SLAB * 2 > CSZ) ? SLAB * 2 : CSZ;
    __shared__ __align__(16) char smem[SMEM];
    __shared__ int s_kt[KSTEPS * 4];
    unsigned short* slab = reinterpret_cast<unsigned short*>(smem);
    unsigned short* s_c  = reinterpret_cast<unsigned short*>(smem);

    const int tid  = threadIdx.x;
    const int mb   = blockIdx.x;
    const int ocb  = blockIdx.y;
    const int nl   = blockIdx.z;
    const int lane = tid & 63;
    const int wv   = tid >> 6;
    const int frow = lane & 15;
    const int fq   = lane >> 4;

    if (tid < KSTEPS * 4) s_kt[tid] = ktab[tid];

    const int p0    = mb * Mblk;
    const int y0    = p0 / W;
    const int plast = (p0 + Mblk < Mtot ? p0 + Mblk : Mtot) - 1;
    const int rows  = plast / W - y0 + KH;

    const unsigned short* in_n =
        inP + (size_t)nl * inSS + (size_t)y0 * Wp * CP;
    const int nchunks = rows * Wp * CPG;
    for (int q = tid; q < nchunks; q += 256) {
        int pix = q / CPG, c8 = q - pix * CPG;
        uint4 v = reinterpret_cast<const uint4*>(in_n)[q];
        *reinterpret_cast<uint4*>(&slab[pix * CL + c8 * 8]) = v;
    }

    int ldsb[MFRAG];
    #pragma unroll
    for (int mf = 0; mf < MFRAG; ++mf) {
        int p  = p0 + mf * 64 + wv * 16 + frow;
        int pc = p < Mtot ? p : (Mtot - 1);
        int y  = pc / W;
        int x  = pc - y * W;
        ldsb[mf] = ((y - y0) * Wp + x) * CL;
    }
    const unsigned short* wbase =
        wPT + ((size_t)(ocb * NOC + frow)) * 32 + fq * 8;

    f32x4 acc[MFRAG][NG];
    #pragma unroll
    for (int mf = 0; mf < MFRAG; ++mf)
        #pragma unroll
        for (int ng = 0; ng < NG; ++ng)
            acc[mf][ng] = (f32x4){0.f, 0.f, 0.f, 0.f};

    __syncthreads();

    for (int kb = 0; kb < KSTEPS; ++kb) {
        int go = s_kt[kb * 4 + fq];
        bf16x8 af[MFRAG];
        #pragma unroll
        for (int mf = 0; mf < MFRAG; ++mf)
            af[mf] = *reinterpret_cast<const bf16x8*>(&slab[ldsb[mf] + go]);
        const unsigned short* wk = wbase + (size_t)kb * COUT * 32;
        #pragma unroll
        for (int ng = 0; ng < NG; ++ng) {
            bf16x8 bf = *reinterpret_cast<const bf16x8*>(wk + ng * 16 * 32);
            #pragma unroll
            for (int mf = 0; mf < MFRAG; ++mf)
                acc[mf][ng] = __builtin_amdgcn_mfma_f32_16x16x32_bf16(
                    af[mf], bf, acc[mf][ng], 0, 0, 0);
        }
    }

    // ---- single-pass epilogue ----
    __syncthreads();            // all waves done with slab
    #pragma unroll
    for (int mf = 0; mf < MFRAG; ++mf) {
        #pragma unroll
        for (int ng = 0; ng < NG; ++ng) {
            float bv = bias[ocb * NOC + ng * 16 + frow];
            #pragma unroll
            for (int j = 0; j < 4; ++j)
                s_c[(mf * 64 + wv * 16 + fq * 4 + j) * LP + ng * 16 + frow] =
                    f2bf(fmaxf(acc[mf][ng][j] + bv, 0.0f));
        }
    }
    __syncthreads();
    unsigned short* out_n = out + (size_t)nl * outSS;
    for (int t = tid; t < Mblk * SEGS; t += 256) {
        int row = t / SEGS, seg = t - row * SEGS;
        int p = p0 + row;
        if (p < Mtot) {
            ushort8 v0 = *reinterpret_cast<const ushort8*>(
                &s_c[row * LP + seg * 16]);
            ushort8 v1 = *reinterpret_cast<const ushort8*>(
                &s_c[row * LP + seg * 16 + 8]);
            unsigned short* op =
                out_n + (size_t)p * COUT + ocb * NOC + seg * 16;
            *reinterpret_cast<ushort8*>(op) = v0;
            *reinterpret_cast<ushort8*>(op + 8) = v1;
        }
    }
}

// ---------------------------------------------------------------------------
// 5) MaxPool 3x3 s2 VALID, HWC, ushort8 + fused halo-zero tail for the
//    output buffer (blocks >= npool do border zeroing; disjoint addresses).
// ---------------------------------------------------------------------------
__global__ __launch_bounds__(256) void pool_border_k(
    const unsigned short* __restrict__ in, unsigned short* __restrict__ out,
    int CG, int C, int W, int inSS,
    int HO, int WO, int Wpo, int outSS, int total,
    int npool, int bHp, int bWp, int bCPG, int bpad, int bnborder, int btotal)
{
    const int b = blockIdx.x;
    const int tidx = threadIdx.x;
    if (b >= npool) {
        border_body(out, bHp, bWp, bCPG, bpad, outSS, bnborder,
                    (b - npool) * 256 + tidx, btotal);
        return;
    }
    int idx = b * 256 + tidx;
    if (idx >= total) return;
    int cg = idx % CG;
    int t  = idx / CG;
    int x  = t % WO;
    t /= WO;
    int y  = t % HO;
    int nl = t / HO;

    const unsigned short* pin = in + (size_t)nl * inSS + cg * 8;
    ushort8 mx = {0,0,0,0,0,0,0,0};
    #pragma unroll
    for (int dy = 0; dy < 3; ++dy)
        #pragma unroll
        for (int dx = 0; dx < 3; ++dx) {
            ushort8 v = *reinterpret_cast<const ushort8*>(
                pin + ((size_t)(2 * y + dy) * W + (2 * x + dx)) * C);
            #pragma unroll
            for (int j = 0; j < 8; ++j) mx[j] = v[j] > mx[j] ? v[j] : mx[j];
        }
    *reinterpret_cast<ushort8*>(
        out + (size_t)nl * outSS +
        ((size_t)(y + 1) * Wpo + (x + 1)) * C + cg * 8) = mx;
}

// ---------------------------------------------------------------------------
// 6) Fused pool2 + GAP, v2 (grid (Bc,8), shfl reduce).
// ---------------------------------------------------------------------------
__global__ __launch_bounds__(256) void pool2gap_k(
    const unsigned short* __restrict__ in, float* __restrict__ out,
    int inSS, int n0)
{
    __shared__ float red[4][4][8];
    const int nl = blockIdx.x;
    const int cg = blockIdx.y;
    const int tid = threadIdx.x;
    const int w  = tid >> 2;
    const int cq = tid & 3;
    const int y = w >> 3, x = w & 7;

    const unsigned short* p = in + (size_t)nl * inSS + cg * 32 + cq * 8;
    ushort8 mx = {0,0,0,0,0,0,0,0};
    #pragma unroll
    for (int dy = 0; dy < 3; ++dy)
        #pragma unroll
        for (int dx = 0; dx < 3; ++dx) {
            ushort8 v = *reinterpret_cast<const ushort8*>(
                p + ((size_t)(2 * y + dy) * 17 + (2 * x + dx)) * 256);
            #pragma unroll
            for (int j = 0; j < 8; ++j) mx[j] = v[j] > mx[j] ? v[j] : mx[j];
        }
    float s[8];
    #pragma unroll
    for (int j = 0; j < 8; ++j) s[j] = bf2f(mx[j]);
    #pragma unroll
    for (int m = 4; m < 64; m <<= 1)
        #pragma unroll
        for (int j = 0; j < 8; ++j)
            s[j] += __shfl_xor(s[j], m);
    if ((tid & 63) < 4) {
        #pragma unroll
        for (int j = 0; j < 8; ++j) red[tid >> 6][tid & 3][j] = s[j];
    }
    __syncthreads();
    if (tid < 32) {
        int cq2 = tid >> 3, j = tid & 7;
        float t = red[0][cq2][j] + red[1][cq2][j] + red[2][cq2][j] + red[3][cq2][j];
        out[(size_t)(n0 + nl) * 256 + cg * 32 + cq2 * 8 + j] = t * (1.0f / 64.0f);
    }
}

// ---------------------------------------------------------------------------
// 7) Fused 3-layer FC head (256->512->256->512), one block per sample
// ---------------------------------------------------------------------------
__global__ __launch_bounds__(256) void fc_fused_k(
    const float* __restrict__ in,
    const float* __restrict__ w0T, const float* __restrict__ b0,
    const float* __restrict__ w1T, const float* __restrict__ b1,
    const float* __restrict__ w2T, const float* __restrict__ b2,
    float* __restrict__ out)
{
    __shared__ float s_in[256], s_h0[512], s_h1[256];
    const int n = blockIdx.x, t = threadIdx.x;
    s_in[t] = in[(size_t)n * 256 + t];
    __syncthreads();
    float a0 = 0.f, a1 = 0.f;
    for (int i = 0; i < 256; ++i) {
        float v = s_in[i];
        a0 += v * w0T[i * 512 + t];
        a1 += v * w0T[i * 512 + t + 256];
    }
    s_h0[t]       = fmaxf(a0 + b0[t], 0.0f);
    s_h0[t + 256] = fmaxf(a1 + b0[t + 256], 0.0f);
    __syncthreads();
    float h = 0.f;
    for (int i = 0; i < 512; ++i) h += s_h0[i] * w1T[i * 256 + t];
    s_h1[t] = fmaxf(h + b1[t], 0.0f);
    __syncthreads();
    a0 = 0.f; a1 = 0.f;
    for (int i = 0; i < 256; ++i) {
        float v = s_h1[i];
        a0 += v * w2T[i * 512 + t];
        a1 += v * w2T[i * 512 + t + 256];
    }
    out[(size_t)n * 512 + t]       = a0 + b2[t];
    out[(size_t)n * 512 + t + 256] = a1 + b2[t + 256];
}

// ---------------------------------------------------------------------------
// Launch. 9 kernels/call.
// ---------------------------------------------------------------------------
extern "C" void kernel_launch(void* const* d_in, const int* in_sizes, int n_in,
                              void* d_out, int out_size, void* d_ws, size_t ws_size,
                              hipStream_t stream)
{
    const int*   X   = (const int*)d_in[0];
    const int*   rm  = (const int*)d_in[1];
    const float* emb = (const float*)d_in[2];
    const float* cw0 = (const float*)d_in[3];
    const float* cb0 = (const float*)d_in[4];
    const float* cw1 = (const float*)d_in[5];
    const float* cb1 = (const float*)d_in[6];
    const float* cw2 = (const float*)d_in[7];
    const float* cb2 = (const float*)d_in[8];
    const float* fw0 = (const float*)d_in[9];
    const float* fb0 = (const float*)d_in[10];
    const float* fw1 = (const float*)d_in[11];
    const float* fb1 = (const float*)d_in[12];
    const float* fw2 = (const float*)d_in[13];
    const float* fb2 = (const float*)d_in[14];
    float* out = (float*)d_out;

    char* p = (char*)d_ws;
    auto alloc = [&](size_t bytes) -> char* {
        char* r = p; p += (bytes + 255) & ~(size_t)255; return r;
    };
    unsigned short* WP0 = (unsigned short*)alloc((size_t)32 * 64 * 32 * 2);
    unsigned short* WP1 = (unsigned short*)alloc((size_t)18 * 128 * 32 * 2);
    unsigned short* WP2 = (unsigned short*)alloc((size_t)36 * 256 * 32 * 2);
    int* KT0 = (int*)alloc(128 * 4);
    int* KT1 = (int*)alloc(72 * 4);
    int* KT2 = (int*)alloc(144 * 4);
    unsigned long long* MASKS = (unsigned long long*)alloc(RR * 8);
    float* W0T  = (float*)alloc((size_t)256 * 512 * 4);
    float* W1T  = (float*)alloc((size_t)512 * 256 * 4);
    float* W2T  = (float*)alloc((size_t)256 * 512 * 4);
    float* GAPB = (float*)alloc((size_t)NB * 256 * 4);
    size_t fixed_bytes = (size_t)(p - (char*)d_ws);

    const size_t A_FL = 231040, B_FL = 331776, C_FL = 133824;   // u16
    const size_t per_sample = (A_FL + B_FL + C_FL) * 2 + 768;
    int Bc = 128;
    while (Bc > 1 && fixed_bytes + (size_t)Bc * per_sample > ws_size) Bc >>= 1;

    unsigned short* bufA = (unsigned short*)alloc((size_t)Bc * A_FL * 2);
    unsigned short* bufC = (unsigned short*)alloc((size_t)Bc * C_FL * 2);
    unsigned short* bufB = (unsigned short*)alloc((size_t)Bc * B_FL * 2);

    // ---- consolidated prep (1 launch) ----
    prep_k<<<3235, 256, 0, stream>>>(
        rm, MASKS, cw0, WP0, cw1, WP1, cw2, WP2,
        KT0, KT1, KT2, fw0, W0T, fw1, W1T, fw2, W2T);

    // ---- chunked pipeline ----
    for (int n0 = 0; n0 < NB; n0 += Bc) {
        // encode (gather) -> A (HWC G [76][76][40], interior +2, halo zeroed)
        encode_k<<<dim3(Bc, 9), 576, 0, stream>>>(X, MASKS, emb, bufA, n0, (int)A_FL);

        // conv0: A -> B  (15 24x16 tiles/sample, COUT=64, 32 ksteps)
        conv0_tile_k<32><<<dim3(15, Bc), 256, 0, stream>>>(
            bufA, WP0, KT0, cb0, bufB, (int)A_FL, (int)B_FL);

        // pool0 + P0p-halo zero: B [72][72][64] -> C P0p [37][37][64]
        {
            int total = Bc * 35 * 35 * 8;
            int npool = (total + 255) / 256;
            int btotal = Bc * 144 * 8;
            int nbord = (btotal + 255) / 256;
            pool_border_k<<<npool + nbord, 256, 0, stream>>>(
                bufB, bufC, 8, 64, 72, (int)B_FL,
                35, 35, 37, (int)C_FL, total,
                npool, 37, 37, 8, 1, 144, btotal);
        }

        // conv1: C -> A  (M=1225, Mblk=256 -> 5 mblocks, COUT=128)
        conv_mfma_k<4, 8, 3, 8, 72, 29304, 18><<<dim3(5, 1, Bc), 256, 0, stream>>>(
            bufC, WP1, KT1, cb1, bufA, 35, 37,
            1225, (int)C_FL, (int)A_FL, 128);

        // pool1 + P1p-halo zero: A [35][35][128] -> C+87616 P1p [19][19][128]
        {
            int total = Bc * 17 * 17 * 16;
            int npool = (total + 255) / 256;
            int btotal = Bc * 72 * 16;
            int nbord = (btotal + 255) / 256;
            pool_border_k<<<npool + nbord, 256, 0, stream>>>(
                bufA, bufC + 87616, 16, 128, 35, (int)A_FL,
                17, 17, 19, (int)C_FL, total,
                npool, 19, 19, 16, 1, 72, btotal);
        }

        // conv2: C+87616 -> B  (M=289, single Mblk=320, 2 oc-blocks,
        //        slab = whole sample input 19x19x136 = 98KB, 256 blocks)
        conv_mfma_k<5, 8, 3, 16, 136, 49096, 36><<<dim3(1, 2, Bc), 256, 0, stream>>>(
            bufC + 87616, WP2, KT2, cb2, bufB, 17, 19,
            289, (int)C_FL, (int)B_FL, 256);

        // fused pool2 + GAP v2: (Bc, 8) blocks -> GAPB fp32
        pool2gap_k<<<dim3(Bc, 8), 256, 0, stream>>>(bufB, GAPB, (int)B_FL, n0);
    }

    // fused FC head
    fc_fused_k<<<NB, 256, 0, stream>>>(GAPB, W0T, fb0, W1T, fb1, W2T, fb2, out);
}

// Round 11
// 414.526 us; speedup vs baseline: 1.1458x; 1.0500x over previous
//
#include <hip/hip_runtime.h>
#include <hip/hip_bf16.h>
#include <cstdint>
#include <cstddef>

#define NB      128
#define RR      300
#define EMB     32

typedef __bf16 bf16x8 __attribute__((ext_vector_type(8)));
typedef float  f32x4  __attribute__((ext_vector_type(4)));
typedef unsigned short ushort8 __attribute__((ext_vector_type(8)));

__device__ __forceinline__ unsigned short f2bf(float f) {
    union { __hip_bfloat16 h; unsigned short u; } c;
    c.h = __float2bfloat16(f);
    return c.u;
}
__device__ __forceinline__ float bf2f(unsigned short u) {
    union { __hip_bfloat16 h; unsigned short u; } c;
    c.u = u;
    return __bfloat162float(c.h);
}

// ---------------------------------------------------------------------------
// helpers for the consolidated prep kernel
// ---------------------------------------------------------------------------
__device__ __forceinline__ void wpack_body(
    const float* __restrict__ w, unsigned short* __restrict__ wPT,
    int COUT, int CIN, int KK, int gpc, int idx, int total)
{
    if (idx >= total) return;
    int kk = idx & 31;
    int t  = idx >> 5;
    int oc = t % COUT;
    int kb = t / COUT;
    int g  = kb * 4 + (kk >> 3);
    int j  = kk & 7;
    int shift = g / gpc;
    int ci    = (g % gpc) * 8 + j;
    float v = (shift < KK && ci < CIN)
        ? w[(size_t)oc * CIN * KK + (size_t)ci * KK + shift] : 0.0f;
    wPT[idx] = f2bf(v);
}

__device__ __forceinline__ void fcT_body(
    const float* __restrict__ w, float* __restrict__ wT, int O, int I, int idx)
{
    if (idx >= O * I) return;
    int i = idx % I, o = idx / I;
    wT[(size_t)i * O + o] = w[idx];
}

// ---------------------------------------------------------------------------
// 1) Consolidated prep: masks + wpack x3 + ktab x3 + fcT x3 in ONE launch.
// ---------------------------------------------------------------------------
__global__ __launch_bounds__(256) void prep_k(
    const int* __restrict__ rm, unsigned long long* __restrict__ masks,
    const float* __restrict__ cw0, unsigned short* __restrict__ WP0,
    const float* __restrict__ cw1, unsigned short* __restrict__ WP1,
    const float* __restrict__ cw2, unsigned short* __restrict__ WP2,
    int* __restrict__ kt0, int* __restrict__ kt1, int* __restrict__ kt2,
    const float* __restrict__ fw0, float* __restrict__ W0T,
    const float* __restrict__ fw1, float* __restrict__ W1T,
    const float* __restrict__ fw2, float* __restrict__ W2T)
{
    const int b = blockIdx.x;
    const int t = threadIdx.x;
    if (b < 2) {
        int r = b * 256 + t;
        if (r < RR) {
            unsigned long long m = 0ull;
            #pragma unroll
            for (int k = 0; k < 64; ++k)
                if (rm[r * 64 + k]) m |= (1ull << k);
            masks[r] = m;
        }
    } else if (b < 258) {
        wpack_body(cw0, WP0, 64, 33, 25, 5, (b - 2) * 256 + t, 32 * 64 * 32);
    } else if (b < 546) {
        wpack_body(cw1, WP1, 128, 64, 9, 8, (b - 258) * 256 + t, 18 * 128 * 32);
    } else if (b < 1698) {
        wpack_body(cw2, WP2, 256, 128, 9, 16, (b - 546) * 256 + t, 36 * 256 * 32);
    } else if (b < 1699) {
        #pragma unroll
        for (int which = 0; which < 3; ++which) {
            int ngr, gpc, K, Wp, CL;
            int* dst;
            if (which == 0)      { ngr = 128; gpc = 5;  K = 5; Wp = 20; CL = 40;  dst = kt0; }
            else if (which == 1) { ngr = 72;  gpc = 8;  K = 3; Wp = 37; CL = 72;  dst = kt1; }
            else                 { ngr = 144; gpc = 16; K = 3; Wp = 19; CL = 136; dst = kt2; }
            if (t < ngr) {
                int shift = t / gpc;
                int off = 0;
                if (shift < K * K) {
                    int ky = shift / K, kx = shift % K;
                    off = (ky * Wp + kx) * CL + (t % gpc) * 8;
                }
                dst[t] = off;
            }
        }
    } else if (b < 2211) {
        fcT_body(fw0, W0T, 512, 256, (b - 1699) * 256 + t);
    } else if (b < 2723) {
        fcT_body(fw1, W1T, 256, 512, (b - 2211) * 256 + t);
    } else {
        fcT_body(fw2, W2T, 512, 256, (b - 2723) * 256 + t);
    }
}

// ---------------------------------------------------------------------------
// 2) border body (used as a tail inside pool launches)
// ---------------------------------------------------------------------------
__device__ __forceinline__ void border_body(
    unsigned short* __restrict__ base, int Hp, int Wp, int CPG, int pad,
    int sampleStride, int nborder, int idx, int total)
{
    if (idx >= total) return;
    int c8 = idx % CPG;
    int t  = idx / CPG;
    int bi = t % nborder;
    int nl = t / nborder;

    int topN = pad * Wp;
    int y, x;
    if (bi < topN) {
        y = bi / Wp; x = bi - y * Wp;
    } else if (bi < 2 * topN) {
        int b2 = bi - topN;
        y = Hp - pad + b2 / Wp; x = b2 % Wp;
    } else {
        int mid = bi - 2 * topN;
        int rowlen = 2 * pad;
        y = pad + mid / rowlen;
        int r = mid % rowlen;
        x = r < pad ? r : Wp - pad + (r - pad);
    }
    uint4 z = make_uint4(0, 0, 0, 0);
    *reinterpret_cast<uint4*>(
        &base[((size_t)nl * sampleStride) +
              ((size_t)y * Wp + x) * (CPG * 8) + c8 * 8]) = z;
}

// ---------------------------------------------------------------------------
// 3) Encode, GATHER version (proven round 5). One thread per output pixel,
//    hot-room list per band, register accumulation, no LDS atomics.
// ---------------------------------------------------------------------------
__global__ __launch_bounds__(576) void encode_k(
    const int* __restrict__ X, const unsigned long long* __restrict__ masks,
    const float* __restrict__ emb, unsigned short* __restrict__ G,
    int n0, int sampleStride)
{
    __shared__ float s_emb[RR * 36];               // 43.2 KB, 16B rows
    __shared__ unsigned s_pos[RR];
    __shared__ unsigned long long s_mask[RR];
    __shared__ unsigned short s_list[320];
    __shared__ int s_woff[9];
    __shared__ int s_cnt;

    const int nl = blockIdx.x, band = blockIdx.y;
    const int by = band * 8;
    const int n  = n0 + nl;
    const int tid = threadIdx.x;

    for (int i = tid; i < RR * 36; i += 576) {
        int r = i / 36, c = i - r * 36;
        float v = 0.0f;
        if (c == 0) v = 1.0f;
        else if (c < 33) v = emb[r * EMB + c - 1];
        s_emb[i] = v;
    }

    const int2* Xp = reinterpret_cast<const int2*>(X);
    bool hot = false;
    if (tid < RR) {
        int2 pos = Xp[n * RR + tid];
        s_pos[tid]  = (unsigned)pos.x | ((unsigned)pos.y << 16);
        s_mask[tid] = masks[tid];
        hot = (pos.y <= by + 7) && (pos.y + 7 >= by);
    }
    unsigned long long bal = __ballot(hot);
    if ((tid & 63) == 0) s_woff[tid >> 6] = (int)__popcll(bal);
    __syncthreads();
    if (tid == 0) {
        int acc = 0;
        #pragma unroll
        for (int w = 0; w < 9; ++w) { int c = s_woff[w]; s_woff[w] = acc; acc += c; }
        s_cnt = acc;
    }
    __syncthreads();
    if (hot) {
        int w = tid >> 6, b = tid & 63;
        unsigned long long before = (b == 0) ? 0ull : (bal & ((1ull << b) - 1ull));
        s_list[s_woff[w] + (int)__popcll(before)] = (unsigned short)tid;
    }
    __syncthreads();

    const int x  = tid % 72;
    const int Y  = by + tid / 72;

    f32x4 acc[9];
    #pragma unroll
    for (int k = 0; k < 9; ++k) acc[k] = (f32x4){0.f, 0.f, 0.f, 0.f};

    const int cnt = s_cnt;
    for (int idx = 0; idx < cnt; ++idx) {
        int r = s_list[idx];
        unsigned pxy = s_pos[r];
        int dxr = x - (int)(pxy & 0xffffu);
        int dyr = Y - (int)(pxy >> 16);
        if (((unsigned)dxr < 8u) && ((unsigned)dyr < 8u) &&
            ((s_mask[r] >> (dxr * 8 + dyr)) & 1ull)) {
            const f32x4* er = reinterpret_cast<const f32x4*>(&s_emb[r * 36]);
            #pragma unroll
            for (int k = 0; k < 9; ++k) acc[k] += er[k];
        }
    }

    unsigned short* Gn = G + (size_t)nl * sampleStride;
    {
        unsigned short o[40];
        #pragma unroll
        for (int k = 0; k < 9; ++k)
            #pragma unroll
            for (int j = 0; j < 4; ++j)
                o[k * 4 + j] = f2bf(acc[k][j]);
        #pragma unroll
        for (int c = 36; c < 40; ++c) o[c] = 0;
        uint4* dst = reinterpret_cast<uint4*>(
            &Gn[((size_t)(Y + 2) * 76 + (x + 2)) * 40]);
        const uint4* src = reinterpret_cast<const uint4*>(o);
        #pragma unroll
        for (int q = 0; q < 5; ++q) dst[q] = src[q];
    }

    uint4 zz4; zz4.x = zz4.y = zz4.z = zz4.w = 0;
    if (tid < 160) {
        int q = tid % 5, cell = tid / 5;
        int ci = cell & 3, rr = cell >> 2;
        int xx = ci < 2 ? ci : 72 + ci;
        uint4* dst = reinterpret_cast<uint4*>(
            &Gn[((size_t)(by + rr + 2) * 76 + xx) * 40]);
        dst[q] = zz4;
    }
    if (band == 0 || band == 8) {
        int rbase = band == 0 ? 0 : 74;
        for (int i = tid; i < 2 * 76 * 5; i += 576) {
            int q = i % 5, cell = i / 5;
            int xx = cell % 76, rr = cell / 76;
            uint4* dst = reinterpret_cast<uint4*>(
                &Gn[((size_t)(rbase + rr) * 76 + xx) * 40]);
            dst[q] = zz4;
        }
    }
}

// ---------------------------------------------------------------------------
// 4a) conv0: 24x16-spatial-tile implicit-GEMM, bf16 MFMA 16x16x32.
//     EXACT round-6 structure (per-kstep wbuf[2][2048] dbuf + swizzle +
//     per-mf epilogue — proven 94.5us; group-2/group-4/reg-prefetch all
//     regressed). ONE change: ldsb[6] replaced by a single runtime base
//     with compile-time per-mf immediate offsets (mf stride 3200 ushorts
//     = 6400B < 64KB ds offset limit). Round-6 was 76 arch + 96 acc =
//     172 regs/wave — 2 regs over the 3-waves/SIMD threshold (170).
//     Freeing the array should drop arch VGPR ~6 -> 3 waves/SIMD,
//     3 blocks/CU (LDS 3x53760 = 161280 <= 163840 fits).
// ---------------------------------------------------------------------------
template<int KSTEPS>
__global__ __launch_bounds__(256, 3) void conv0_tile_k(
    const unsigned short* __restrict__ inP,
    const unsigned short* __restrict__ wPT,
    const int* __restrict__ ktab,
    const float* __restrict__ bias,
    unsigned short* __restrict__ out,
    int inSS, int outSS)
{
    constexpr int CL = 40;
    constexpr int LP = 72;
    __shared__ __align__(16) unsigned short slab[28 * 20 * CL];  // 44.8 KB
    __shared__ __align__(16) unsigned short wbuf[2][2048];       // 8 KB dbuf
    __shared__ int s_kt[KSTEPS * 4];
    unsigned short* s_c = slab;

    const int tid = threadIdx.x;
    const int tl  = blockIdx.x;
    const int nl  = blockIdx.y;
    const int tyi = tl / 5, txi = tl % 5;
    const int y0 = tyi * 24;
    const int x0 = txi < 4 ? txi * 16 : 56;

    const int lane = tid & 63, wv = tid >> 6, frow = lane & 15, fq = lane >> 4;

    if (tid < KSTEPS * 4) s_kt[tid] = ktab[tid];

    // swizzled global source offset (round-6 proven): physical LDS slot
    // P = wv*1KB + lane*16B holds logical L = P ^ (key<<4), key=(lane>>3)&7
    const int wsrc = wv * 512 + ((lane ^ ((lane >> 3) & 7)) * 8);

    // async stage of kstep-0 weights (swizzled source, linear LDS dest)
    {
        const unsigned short* src = wPT + wsrc;
        __builtin_amdgcn_global_load_lds(
            (const __attribute__((address_space(1))) void*)src,
            (__attribute__((address_space(3))) void*)&wbuf[0][wv * 512],
            16, 0, 0);
    }

    const unsigned short* in_n = inP + (size_t)nl * inSS;
    {
        const uint4* src = reinterpret_cast<const uint4*>(in_n);
        uint4* dst = reinterpret_cast<uint4*>(slab);
        #pragma unroll
        for (int it = 0; it < 11; ++it) {
            int q = tid + it * 256;
            if (q < 2800) {
                int r = q / 100, c = q - r * 100;
                dst[q] = src[((y0 + r) * 76 + x0) * 5 + c];
            }
        }
    }

    // single A-address base; per-mf offset is the compile-time constant
    // mf*3200 ushorts (= 6400B), folded into ds_read offset: immediates.
    const int abase = (wv * 20 + frow) * CL;

    // swizzled read offset within the 4KB weight tile, ng added as +512
    const int wrd = ((frow * 64 + fq * 16) ^ (((frow >> 1) & 7) << 4)) >> 1;

    f32x4 acc[6][4];
    #pragma unroll
    for (int a = 0; a < 6; ++a)
        #pragma unroll
        for (int b = 0; b < 4; ++b) acc[a][b] = (f32x4){0.f, 0.f, 0.f, 0.f};

    __syncthreads();   // drains vmcnt: wbuf[0] + slab ready

    #pragma unroll 2
    for (int kb = 0; kb < KSTEPS; ++kb) {
        const int cur = kb & 1;
        if (kb + 1 < KSTEPS) {
            const unsigned short* src =
                wPT + (size_t)(kb + 1) * 2048 + wsrc;
            __builtin_amdgcn_global_load_lds(
                (const __attribute__((address_space(1))) void*)src,
                (__attribute__((address_space(3))) void*)&wbuf[cur ^ 1][wv * 512],
                16, 0, 0);
        }
        const unsigned short* ap = &slab[abase + s_kt[kb * 4 + fq]];
        bf16x8 af[6];
        #pragma unroll
        for (int mf = 0; mf < 6; ++mf)
            af[mf] = *reinterpret_cast<const bf16x8*>(ap + mf * 3200);
        const unsigned short* wl = &wbuf[cur][wrd];
        #pragma unroll
        for (int ng = 0; ng < 4; ++ng) {
            bf16x8 bf = *reinterpret_cast<const bf16x8*>(&wl[ng * 512]);
            #pragma unroll
            for (int mf = 0; mf < 6; ++mf)
                acc[mf][ng] = __builtin_amdgcn_mfma_f32_16x16x32_bf16(
                    af[mf], bf, acc[mf][ng], 0, 0, 0);
        }
        __syncthreads();
    }

    unsigned short* out_n = out + (size_t)nl * outSS;
    const int erow = tid >> 2, eseg = tid & 3;
    #pragma unroll
    for (int mf = 0; mf < 6; ++mf) {
        __syncthreads();
        #pragma unroll
        for (int ng = 0; ng < 4; ++ng) {
            float bv = bias[ng * 16 + frow];
            #pragma unroll
            for (int j = 0; j < 4; ++j)
                s_c[(wv * 16 + fq * 4 + j) * LP + ng * 16 + frow] =
                    f2bf(fmaxf(acc[mf][ng][j] + bv, 0.0f));
        }
        __syncthreads();
        {
            int ty = mf * 4 + (erow >> 4);
            int tx = erow & 15;
            int pos = (y0 + ty) * 72 + (x0 + tx);
            ushort8 v0 = *reinterpret_cast<const ushort8*>(
                &s_c[erow * LP + eseg * 16]);
            ushort8 v1 = *reinterpret_cast<const ushort8*>(
                &s_c[erow * LP + eseg * 16 + 8]);
            unsigned short* op = out_n + (size_t)pos * 64 + eseg * 16;
            *reinterpret_cast<ushort8*>(op) = v0;
            *reinterpret_cast<ushort8*>(op + 8) = v1;
        }
    }
}

// ---------------------------------------------------------------------------
// 4b) Generic row-slab implicit-GEMM conv (conv1/conv2), bf16 MFMA 16x16x32.
//     Single-pass epilogue (kept: it improved conv1/conv2 in round 1).
// ---------------------------------------------------------------------------
template<int MFRAG, int NG, int KH, int CPG, int CL, int SLAB, int KSTEPS>
__global__ __launch_bounds__(256, 2) void conv_mfma_k(
    const unsigned short* __restrict__ inP,
    const unsigned short* __restrict__ wPT,
    const int* __restrict__ ktab,
    const float* __restrict__ bias,
    unsigned short* __restrict__ out,
    int W, int Wp, int Mtot, int inSS, int outSS, int COUT)
{
    constexpr int Mblk = MFRAG * 64;
    constexpr int NOC  = NG * 16;
    constexpr int SEGS = NOC / 16;
    constexpr int LP   = NOC + 8;
    constexpr int CP   = CPG * 8;
    constexpr int CSZ  = Mblk * LP * 2;
    constexpr int SMEM = (SLAB * 2 > CSZ) ? SLAB * 2 : CSZ;
    __shared__ __align__(16) char smem[SMEM];
    __shared__ int s_kt[KSTEPS * 4];
    unsigned short* slab = reinterpret_cast<unsigned short*>(smem);
    unsigned short* s_c  = reinterpret_cast<unsigned short*>(smem);

    const int tid  = threadIdx.x;
    const int mb   = blockIdx.x;
    const int ocb  = blockIdx.y;
    const int nl   = blockIdx.z;
    const int lane = tid & 63;
    const int wv   = tid >> 6;
    const int frow = lane & 15;
    const int fq   = lane >> 4;

    if (tid < KSTEPS * 4) s_kt[tid] = ktab[tid];

    const int p0    = mb * Mblk;
    const int y0    = p0 / W;
    const int plast = (p0 + Mblk < Mtot ? p0 + Mblk : Mtot) - 1;
    const int rows  = plast / W - y0 + KH;

    const unsigned short* in_n =
        inP + (size_t)nl * inSS + (size_t)y0 * Wp * CP;
    const int nchunks = rows * Wp * CPG;
    for (int q = tid; q < nchunks; q += 256) {
        int pix = q / CPG, c8 = q - pix * CPG;
        uint4 v = reinterpret_cast<const uint4*>(in_n)[q];
        *reinterpret_cast<uint4*>(&slab[pix * CL + c8 * 8]) = v;
    }

    int ldsb[MFRAG];
    #pragma unroll
    for (int mf = 0; mf < MFRAG; ++mf) {
        int p  = p0 + mf * 64 + wv * 16 + frow;
        int pc = p < Mtot ? p : (Mtot - 1);
        int y  = pc / W;
        int x  = pc - y * W;
        ldsb[mf] = ((y - y0) * Wp + x) * CL;
    }
    const unsigned short* wbase =
        wPT + ((size_t)(ocb * NOC + frow)) * 32 + fq * 8;

    f32x4 acc[MFRAG][NG];
    #pragma unroll
    for (int mf = 0; mf < MFRAG; ++mf)
        #pragma unroll
        for (int ng = 0; ng < NG; ++ng)
            acc[mf][ng] = (f32x4){0.f, 0.f, 0.f, 0.f};

    __syncthreads();

    for (int kb = 0; kb < KSTEPS; ++kb) {
        int go = s_kt[kb * 4 + fq];
        bf16x8 af[MFRAG];
        #pragma unroll
        for (int mf = 0; mf < MFRAG; ++mf)
            af[mf] = *reinterpret_cast<const bf16x8*>(&slab[ldsb[mf] + go]);
        const unsigned short* wk = wbase + (size_t)kb * COUT * 32;
        #pragma unroll
        for (int ng = 0; ng < NG; ++ng) {
            bf16x8 bf = *reinterpret_cast<const bf16x8*>(wk + ng * 16 * 32);
            #pragma unroll
            for (int mf = 0; mf < MFRAG; ++mf)
                acc[mf][ng] = __builtin_amdgcn_mfma_f32_16x16x32_bf16(
                    af[mf], bf, acc[mf][ng], 0, 0, 0);
        }
    }

    // ---- single-pass epilogue ----
    __syncthreads();            // all waves done with slab
    #pragma unroll
    for (int mf = 0; mf < MFRAG; ++mf) {
        #pragma unroll
        for (int ng = 0; ng < NG; ++ng) {
            float bv = bias[ocb * NOC + ng * 16 + frow];
            #pragma unroll
            for (int j = 0; j < 4; ++j)
                s_c[(mf * 64 + wv * 16 + fq * 4 + j) * LP + ng * 16 + frow] =
                    f2bf(fmaxf(acc[mf][ng][j] + bv, 0.0f));
        }
    }
    __syncthreads();
    unsigned short* out_n = out + (size_t)nl * outSS;
    for (int t = tid; t < Mblk * SEGS; t += 256) {
        int row = t / SEGS, seg = t - row * SEGS;
        int p = p0 + row;
        if (p < Mtot) {
            ushort8 v0 = *reinterpret_cast<const ushort8*>(
                &s_c[row * LP + seg * 16]);
            ushort8 v1 = *reinterpret_cast<const ushort8*>(
                &s_c[row * LP + seg * 16 + 8]);
            unsigned short* op =
                out_n + (size_t)p * COUT + ocb * NOC + seg * 16;
            *reinterpret_cast<ushort8*>(op) = v0;
            *reinterpret_cast<ushort8*>(op + 8) = v1;
        }
    }
}

// ---------------------------------------------------------------------------
// 5) MaxPool 3x3 s2 VALID, HWC, ushort8 + fused halo-zero tail for the
//    output buffer (blocks >= npool do border zeroing; disjoint addresses).
// ---------------------------------------------------------------------------
__global__ __launch_bounds__(256) void pool_border_k(
    const unsigned short* __restrict__ in, unsigned short* __restrict__ out,
    int CG, int C, int W, int inSS,
    int HO, int WO, int Wpo, int outSS, int total,
    int npool, int bHp, int bWp, int bCPG, int bpad, int bnborder, int btotal)
{
    const int b = blockIdx.x;
    const int tidx = threadIdx.x;
    if (b >= npool) {
        border_body(out, bHp, bWp, bCPG, bpad, outSS, bnborder,
                    (b - npool) * 256 + tidx, btotal);
        return;
    }
    int idx = b * 256 + tidx;
    if (idx >= total) return;
    int cg = idx % CG;
    int t  = idx / CG;
    int x  = t % WO;
    t /= WO;
    int y  = t % HO;
    int nl = t / HO;

    const unsigned short* pin = in + (size_t)nl * inSS + cg * 8;
    ushort8 mx = {0,0,0,0,0,0,0,0};
    #pragma unroll
    for (int dy = 0; dy < 3; ++dy)
        #pragma unroll
        for (int dx = 0; dx < 3; ++dx) {
            ushort8 v = *reinterpret_cast<const ushort8*>(
                pin + ((size_t)(2 * y + dy) * W + (2 * x + dx)) * C);
            #pragma unroll
            for (int j = 0; j < 8; ++j) mx[j] = v[j] > mx[j] ? v[j] : mx[j];
        }
    *reinterpret_cast<ushort8*>(
        out + (size_t)nl * outSS +
        ((size_t)(y + 1) * Wpo + (x + 1)) * C + cg * 8) = mx;
}

// ---------------------------------------------------------------------------
// 6) Fused pool2 + GAP, v2 (grid (Bc,8), shfl reduce).
// ---------------------------------------------------------------------------
__global__ __launch_bounds__(256) void pool2gap_k(
    const unsigned short* __restrict__ in, float* __restrict__ out,
    int inSS, int n0)
{
    __shared__ float red[4][4][8];
    const int nl = blockIdx.x;
    const int cg = blockIdx.y;
    const int tid = threadIdx.x;
    const int w  = tid >> 2;
    const int cq = tid & 3;
    const int y = w >> 3, x = w & 7;

    const unsigned short* p = in + (size_t)nl * inSS + cg * 32 + cq * 8;
    ushort8 mx = {0,0,0,0,0,0,0,0};
    #pragma unroll
    for (int dy = 0; dy < 3; ++dy)
        #pragma unroll
        for (int dx = 0; dx < 3; ++dx) {
            ushort8 v = *reinterpret_cast<const ushort8*>(
                p + ((size_t)(2 * y + dy) * 17 + (2 * x + dx)) * 256);
            #pragma unroll
            for (int j = 0; j < 8; ++j) mx[j] = v[j] > mx[j] ? v[j] : mx[j];
        }
    float s[8];
    #pragma unroll
    for (int j = 0; j < 8; ++j) s[j] = bf2f(mx[j]);
    #pragma unroll
    for (int m = 4; m < 64; m <<= 1)
        #pragma unroll
        for (int j = 0; j < 8; ++j)
            s[j] += __shfl_xor(s[j], m);
    if ((tid & 63) < 4) {
        #pragma unroll
        for (int j = 0; j < 8; ++j) red[tid >> 6][tid & 3][j] = s[j];
    }
    __syncthreads();
    if (tid < 32) {
        int cq2 = tid >> 3, j = tid & 7;
        float t = red[0][cq2][j] + red[1][cq2][j] + red[2][cq2][j] + red[3][cq2][j];
        out[(size_t)(n0 + nl) * 256 + cg * 32 + cq2 * 8 + j] = t * (1.0f / 64.0f);
    }
}

// ---------------------------------------------------------------------------
// 7) Fused 3-layer FC head (256->512->256->512), one block per sample
// ---------------------------------------------------------------------------
__global__ __launch_bounds__(256) void fc_fused_k(
    const float* __restrict__ in,
    const float* __restrict__ w0T, const float* __restrict__ b0,
    const float* __restrict__ w1T, const float* __restrict__ b1,
    const float* __restrict__ w2T, const float* __restrict__ b2,
    float* __restrict__ out)
{
    __shared__ float s_in[256], s_h0[512], s_h1[256];
    const int n = blockIdx.x, t = threadIdx.x;
    s_in[t] = in[(size_t)n * 256 + t];
    __syncthreads();
    float a0 = 0.f, a1 = 0.f;
    for (int i = 0; i < 256; ++i) {
        float v = s_in[i];
        a0 += v * w0T[i * 512 + t];
        a1 += v * w0T[i * 512 + t + 256];
    }
    s_h0[t]       = fmaxf(a0 + b0[t], 0.0f);
    s_h0[t + 256] = fmaxf(a1 + b0[t + 256], 0.0f);
    __syncthreads();
    float h = 0.f;
    for (int i = 0; i < 512; ++i) h += s_h0[i] * w1T[i * 256 + t];
    s_h1[t] = fmaxf(h + b1[t], 0.0f);
    __syncthreads();
    a0 = 0.f; a1 = 0.f;
    for (int i = 0; i < 256; ++i) {
        float v = s_h1[i];
        a0 += v * w2T[i * 512 + t];
        a1 += v * w2T[i * 512 + t + 256];
    }
    out[(size_t)n * 512 + t]       = a0 + b2[t];
    out[(size_t)n * 512 + t + 256] = a1 + b2[t + 256];
}

// ---------------------------------------------------------------------------
// Launch. 9 kernels/call.
// ---------------------------------------------------------------------------
extern "C" void kernel_launch(void* const* d_in, const int* in_sizes, int n_in,
                              void* d_out, int out_size, void* d_ws, size_t ws_size,
                              hipStream_t stream)
{
    const int*   X   = (const int*)d_in[0];
    const int*   rm  = (const int*)d_in[1];
    const float* emb = (const float*)d_in[2];
    const float* cw0 = (const float*)d_in[3];
    const float* cb0 = (const float*)d_in[4];
    const float* cw1 = (const float*)d_in[5];
    const float* cb1 = (const float*)d_in[6];
    const float* cw2 = (const float*)d_in[7];
    const float* cb2 = (const float*)d_in[8];
    const float* fw0 = (const float*)d_in[9];
    const float* fb0 = (const float*)d_in[10];
    const float* fw1 = (const float*)d_in[11];
    const float* fb1 = (const float*)d_in[12];
    const float* fw2 = (const float*)d_in[13];
    const float* fb2 = (const float*)d_in[14];
    float* out = (float*)d_out;

    char* p = (char*)d_ws;
    auto alloc = [&](size_t bytes) -> char* {
        char* r = p; p += (bytes + 255) & ~(size_t)255; return r;
    };
    unsigned short* WP0 = (unsigned short*)alloc((size_t)32 * 64 * 32 * 2);
    unsigned short* WP1 = (unsigned short*)alloc((size_t)18 * 128 * 32 * 2);
    unsigned short* WP2 = (unsigned short*)alloc((size_t)36 * 256 * 32 * 2);
    int* KT0 = (int*)alloc(128 * 4);
    int* KT1 = (int*)alloc(72 * 4);
    int* KT2 = (int*)alloc(144 * 4);
    unsigned long long* MASKS = (unsigned long long*)alloc(RR * 8);
    float* W0T  = (float*)alloc((size_t)256 * 512 * 4);
    float* W1T  = (float*)alloc((size_t)512 * 256 * 4);
    float* W2T  = (float*)alloc((size_t)256 * 512 * 4);
    float* GAPB = (float*)alloc((size_t)NB * 256 * 4);
    size_t fixed_bytes = (size_t)(p - (char*)d_ws);

    const size_t A_FL = 231040, B_FL = 331776, C_FL = 133824;   // u16
    const size_t per_sample = (A_FL + B_FL + C_FL) * 2 + 768;
    int Bc = 128;
    while (Bc > 1 && fixed_bytes + (size_t)Bc * per_sample > ws_size) Bc >>= 1;

    unsigned short* bufA = (unsigned short*)alloc((size_t)Bc * A_FL * 2);
    unsigned short* bufC = (unsigned short*)alloc((size_t)Bc * C_FL * 2);
    unsigned short* bufB = (unsigned short*)alloc((size_t)Bc * B_FL * 2);

    // ---- consolidated prep (1 launch) ----
    prep_k<<<3235, 256, 0, stream>>>(
        rm, MASKS, cw0, WP0, cw1, WP1, cw2, WP2,
        KT0, KT1, KT2, fw0, W0T, fw1, W1T, fw2, W2T);

    // ---- chunked pipeline ----
    for (int n0 = 0; n0 < NB; n0 += Bc) {
        // encode (gather) -> A (HWC G [76][76][40], interior +2, halo zeroed)
        encode_k<<<dim3(Bc, 9), 576, 0, stream>>>(X, MASKS, emb, bufA, n0, (int)A_FL);

        // conv0: A -> B  (15 24x16 tiles/sample, COUT=64, 32 ksteps)
        conv0_tile_k<32><<<dim3(15, Bc), 256, 0, stream>>>(
            bufA, WP0, KT0, cb0, bufB, (int)A_FL, (int)B_FL);

        // pool0 + P0p-halo zero: B [72][72][64] -> C P0p [37][37][64]
        {
            int total = Bc * 35 * 35 * 8;
            int npool = (total + 255) / 256;
            int btotal = Bc * 144 * 8;
            int nbord = (btotal + 255) / 256;
            pool_border_k<<<npool + nbord, 256, 0, stream>>>(
                bufB, bufC, 8, 64, 72, (int)B_FL,
                35, 35, 37, (int)C_FL, total,
                npool, 37, 37, 8, 1, 144, btotal);
        }

        // conv1: C -> A  (M=1225, Mblk=256 -> 5 mblocks, COUT=128)
        conv_mfma_k<4, 8, 3, 8, 72, 29304, 18><<<dim3(5, 1, Bc), 256, 0, stream>>>(
            bufC, WP1, KT1, cb1, bufA, 35, 37,
            1225, (int)C_FL, (int)A_FL, 128);

        // pool1 + P1p-halo zero: A [35][35][128] -> C+87616 P1p [19][19][128]
        {
            int total = Bc * 17 * 17 * 16;
            int npool = (total + 255) / 256;
            int btotal = Bc * 72 * 16;
            int nbord = (btotal + 255) / 256;
            pool_border_k<<<npool + nbord, 256, 0, stream>>>(
                bufA, bufC + 87616, 16, 128, 35, (int)A_FL,
                17, 17, 19, (int)C_FL, total,
                npool, 19, 19, 16, 1, 72, btotal);
        }

        // conv2: C+87616 -> B  (M=289, single Mblk=320, 2 oc-blocks,
        //        slab = whole sample input 19x19x136 = 98KB, 256 blocks)
        conv_mfma_k<5, 8, 3, 16, 136, 49096, 36><<<dim3(1, 2, Bc), 256, 0, stream>>>(
            bufC + 87616, WP2, KT2, cb2, bufB, 17, 19,
            289, (int)C_FL, (int)B_FL, 256);

        // fused pool2 + GAP v2: (Bc, 8) blocks -> GAPB fp32
        pool2gap_k<<<dim3(Bc, 8), 256, 0, stream>>>(bufB, GAPB, (int)B_FL, n0);
    }

    // fused FC head
    fc_fused_k<<<NB, 256, 0, stream>>>(GAPB, W0T, fb0, W1T, fb1, W2T, fb2, out);
}